// Round 22
// baseline (295.054 us; speedup 1.0000x reference)
//
#include <hip/hip_runtime.h>
#include <hip/hip_bf16.h>

#define N_ 2
#define C_ 192
#define CB_ 64
#define HW_ 100
#define PIX_ (HW_*HW_)
#define PADW_ 102
#define PADPIX_ (PADW_*PADW_)
#define KTOT_ 1728
#define KPOS_ 576
#define QSCALE_ 0.3606737602222409f   // 0.25 * log2(e)

typedef __attribute__((ext_vector_type(8))) short bf16x8;
typedef __attribute__((ext_vector_type(4))) short bf16x4;
typedef __attribute__((ext_vector_type(4))) float f32x4;

#if defined(__has_builtin)
#if __has_builtin(__builtin_amdgcn_mfma_f32_16x16x16bf16_1k)
#define HAVE_MFMA16 1
#endif
#if __has_builtin(__builtin_amdgcn_exp2f)
#define EXP2(x) __builtin_amdgcn_exp2f(x)
#endif
#endif
#ifndef EXP2
#define EXP2(x) exp2f(x)
#endif

static __device__ __forceinline__ float bn_scale(float g) {
    return g * rsqrtf(1.0f + 1e-5f);
}

static __device__ __forceinline__ unsigned short f2bf(float v) {
    __hip_bfloat16 h = __float2bfloat16(v);
    return *(unsigned short*)&h;
}

// ---------------- prep: fp32 NCHW x -> bf16 channel-last [n][PIX][192] --------
__global__ __launch_bounds__(256) void x_nhwc_k(
    const float* __restrict__ in, unsigned short* __restrict__ out)
{
    int idx = blockIdx.x * 256 + threadIdx.x;
    if (idx >= N_ * 4 * PIX_) return;
    int p     = idx % PIX_;
    int chunk = (idx / PIX_) & 3;
    int n     = idx / (PIX_ * 4);
    int c0 = chunk * 48;
    const float* ip = in + ((size_t)n * C_ + c0) * PIX_ + p;
    unsigned short vals[48];
    #pragma unroll
    for (int j = 0; j < 48; ++j) vals[j] = f2bf(ip[(size_t)j * PIX_]);
    unsigned short* op = out + ((size_t)n * PIX_ + p) * 192 + c0;
    #pragma unroll
    for (int v = 0; v < 6; ++v) {
        bf16x8 pack;
        #pragma unroll
        for (int j = 0; j < 8; ++j) pack[j] = (short)vals[v * 8 + j];
        *(bf16x8*)(op + v * 8) = pack;
    }
}

// ---------------- conv1x1 + BN as GEMM, bf16 MFMA, NHWC input ----------------
__global__ __launch_bounds__(256) void conv1x1_mfma_k(
    const unsigned short* __restrict__ Xc,
    const float* __restrict__ w,
    const float* __restrict__ g, const float* __restrict__ bb,
    float* __restrict__ out)
{
    __shared__ unsigned short lds[64][72];
    int tid  = threadIdx.x;
    int lane = tid & 63;
    int wv   = tid >> 6;
    int c    = lane & 15;
    int g8   = (lane >> 4) * 8;
    int p0   = blockIdx.x * 64;
    int co0  = blockIdx.y * 64;
    int n    = blockIdx.z;

    int sp = tid >> 2;
    int sk = (tid & 3) * 8;
    int pc = min(p0 + sp, PIX_ - 1);
    const unsigned short* bp = Xc + ((size_t)n * PIX_ + pc) * 192;

    const float* arow = w + (size_t)(co0 + wv * 16 + c) * C_;

    f32x4 acc[4];
    #pragma unroll
    for (int f = 0; f < 4; ++f) acc[f] = (f32x4){0.f, 0.f, 0.f, 0.f};

    bf16x8 b0 = *(const bf16x8*)(bp + sk);
    bf16x8 b1 = *(const bf16x8*)(bp + 32 + sk);

    for (int k0 = 0; k0 < C_; k0 += 64) {
        __syncthreads();
        *(bf16x8*)(&lds[sp][sk])      = b0;
        *(bf16x8*)(&lds[sp][32 + sk]) = b1;
        __syncthreads();
        if (k0 + 64 < C_) {
            b0 = *(const bf16x8*)(bp + k0 + 64 + sk);
            b1 = *(const bf16x8*)(bp + k0 + 96 + sk);
        }
        #pragma unroll
        for (int h = 0; h < 2; ++h) {
            bf16x8 a;
            const float* ap = arow + k0 + h * 32 + g8;
            #pragma unroll
            for (int j = 0; j < 8; ++j) a[j] = (short)f2bf(ap[j]);
            #pragma unroll
            for (int f = 0; f < 4; ++f) {
                bf16x8 b = *(const bf16x8*)(&lds[f * 16 + c][h * 32 + g8]);
                acc[f] = __builtin_amdgcn_mfma_f32_16x16x32_bf16(a, b, acc[f], 0, 0, 0);
            }
        }
    }

    #pragma unroll
    for (int f = 0; f < 4; ++f) {
        int p = p0 + f * 16 + c;
        if (p < PIX_) {
            #pragma unroll
            for (int r = 0; r < 4; ++r) {
                int co = co0 + wv * 16 + (lane >> 4) * 4 + r;
                out[(size_t)(n * C_ + co) * PIX_ + p] = acc[f][r] * bn_scale(g[co]) + bb[co];
            }
        }
    }
}

// ---------------- combined weight converts (pos + conv2 + conv3) -------------
__global__ __launch_bounds__(256) void wcvt_all_k(
    const float* __restrict__ pw, const float* __restrict__ w2,
    const float* __restrict__ w3,
    unsigned short* __restrict__ pwb, unsigned short* __restrict__ w2b,
    unsigned short* __restrict__ w3b)
{
    int idx = blockIdx.x * 256 + threadIdx.x;
    const int S0 = CB_ * KPOS_;          // 36864
    const int S1 = S0 + C_ * KTOT_;      // 368640
    const int S2 = S1 + C_ * KTOT_;      // 700416
    if (idx < S0) {
        int t = idx % 9, ci = (idx / 9) % CB_, co = idx / (9 * CB_);
        pwb[(size_t)co * KPOS_ + t * CB_ + ci] = f2bf(pw[idx]);
    } else if (idx < S1) {
        int k = idx - S0;
        int t = k % 9, ci = (k / 9) % C_, co = k / (9 * C_);
        w2b[(size_t)co * KTOT_ + t * C_ + ci] = f2bf(w2[k]);
    } else if (idx < S2) {
        int k = idx - S1;
        int t = k % 9, ci = (k / 9) % C_, co = k / (9 * C_);
        w3b[(size_t)co * KTOT_ + t * C_ + ci] = f2bf(w3[k]);
    }
}

// ---------------- combined gather (all 3 chunks) ------------------------------
template<int NW, int SH, int KH>
__device__ __forceinline__ void gather_body(
    const float* __restrict__ x1, float* __restrict__ U, int f, int cidx)
{
    int t = f;
    int j = t % NW; t /= NW;
    int i = t % NW; t /= NW;
    int c = t % KH; t /= KH;
    int r = t % KH; t /= KH;
    int cb = t % CB_;
    int n  = t / CB_;
    int hh = i * SH + r;
    int ww = j * SH + c;
    U[f] = x1[((n * C_ + cidx * CB_ + cb) * HW_ + hh) * HW_ + ww];
}

__global__ __launch_bounds__(256) void gather_c_k(
    const float* __restrict__ x1, float* __restrict__ Uall)
{
    int gid = blockIdx.x * 256 + threadIdx.x;
    if (gid < 1280000)       gather_body<4, 25, 25>(x1, Uall,            gid,            0);
    else if (gid < 3377152)  gather_body<8, 12, 16>(x1, Uall + 1280000,  gid - 1280000,  1);
    else if (gid < 6031360)  gather_body<12, 8, 12>(x1, Uall + 3377152,  gid - 3377152,  2);
}

// ---------------- fused q/k/v GEMM body (templated L) -------------------------
template<int L, int LP, int NPIX>
__device__ __forceinline__ void qkv_body(
    unsigned short (*lds)[72],
    const float* __restrict__ U,
    const float* __restrict__ qw, const float* __restrict__ kw,
    const float* __restrict__ vw,
    unsigned short* __restrict__ Q, unsigned short* __restrict__ Kt,
    unsigned short* __restrict__ V, int bid)
{
    int tid  = threadIdx.x;
    int lane = tid & 63;
    int wv   = tid >> 6;
    int c    = lane & 15;
    int g8   = (lane >> 4) * 8;
    int q0   = bid * 64;

    int sp = tid >> 2;
    int sk = (tid & 3) * 8;
    int qc = min(q0 + sp, NPIX - 1);
    int b  = qc / L, p = qc % L;
    const float* ub = U + (size_t)b * 64 * L + p;

    bf16x8 b0, b1;
    #pragma unroll
    for (int j = 0; j < 8; ++j) {
        b0[j] = (short)f2bf(ub[(size_t)(sk + j) * L]);
        b1[j] = (short)f2bf(ub[(size_t)(32 + sk + j) * L]);
    }
    __syncthreads();
    *(bf16x8*)(&lds[sp][sk])      = b0;
    *(bf16x8*)(&lds[sp][32 + sk]) = b1;
    __syncthreads();

    f32x4 acc[3][4];
    #pragma unroll
    for (int s = 0; s < 3; ++s)
        #pragma unroll
        for (int f = 0; f < 4; ++f) acc[s][f] = (f32x4){0.f, 0.f, 0.f, 0.f};

    const float* wbase[3] = {qw, kw, vw};
    #pragma unroll
    for (int s = 0; s < 3; ++s) {
        const float* arow = wbase[s] + (size_t)(wv * 16 + c) * 64;
        #pragma unroll
        for (int h = 0; h < 2; ++h) {
            bf16x8 a;
            const float* ap = arow + h * 32 + g8;
            #pragma unroll
            for (int j = 0; j < 8; ++j) a[j] = (short)f2bf(ap[j]);
            #pragma unroll
            for (int f = 0; f < 4; ++f) {
                bf16x8 bfr = *(const bf16x8*)(&lds[f * 16 + c][h * 32 + g8]);
                acc[s][f] = __builtin_amdgcn_mfma_f32_16x16x32_bf16(a, bfr, acc[s][f], 0, 0, 0);
            }
        }
    }

    #pragma unroll
    for (int f = 0; f < 4; ++f) {
        int qq = q0 + f * 16 + c;
        if (qq < NPIX) {
            int bo = qq / L, po = qq % L;
            #pragma unroll
            for (int r = 0; r < 4; ++r) {
                int co = wv * 16 + (lane >> 4) * 4 + r;
                Q[(size_t)(bo * 64 + co) * L + po] = f2bf(acc[0][f][r] * QSCALE_);
                Kt[((size_t)(bo * 4 + wv) * L + po) * 16 + ((lane >> 4) * 4 + r)] = f2bf(acc[1][f][r]);
                V[(size_t)(bo * 64 + co) * LP + po] = f2bf(acc[2][f][r]);
            }
        }
    }
}

__global__ __launch_bounds__(256) void qkv_c_k(
    const float* __restrict__ Uall,
    const float* __restrict__ qw, const float* __restrict__ kw,
    const float* __restrict__ vw,
    unsigned short* __restrict__ Qa, unsigned short* __restrict__ Ka,
    unsigned short* __restrict__ Va)
{
    __shared__ unsigned short lds[64][72];
    int bid = blockIdx.x;
    if (bid < 313)
        qkv_body<625, 632, 20000>(lds, Uall, qw, kw, vw, Qa, Ka, Va, bid);
    else if (bid < 825)
        qkv_body<256, 256, 32768>(lds, Uall + 1280000, qw, kw, vw,
                                  Qa + 1280000, Ka + 1280000, Va + 1294336, bid - 313);
    else
        qkv_body<144, 144, 41472>(lds, Uall + 3377152, qw, kw, vw,
                                  Qa + 3377152, Ka + 3377152, Va + 3391488, bid - 825);
}

// ---------------- attention tile body (MASK only for the tail tile) -----------
template<int L, int LP, bool MASK>
__device__ __forceinline__ void attn_tile(
    int m0, const unsigned short* __restrict__ kb,
    const unsigned short* __restrict__ vb, int c, int g,
#ifdef HAVE_MFMA16
    const bf16x4* qf,
#else
    const bf16x8* qf,
#endif
    f32x4* acc, float* mrun, float* srun)
{
    float p[2][16];
#ifdef HAVE_MFMA16
    #pragma unroll
    for (int t = 0; t < 4; ++t) {
        int mm = m0 + c + t * 16;
        if (MASK) mm = min(mm, L - 1);
        bf16x4 kf = *(const bf16x4*)(kb + (size_t)mm * 16 + g * 4);   // shared
        f32x4 s0 = __builtin_amdgcn_mfma_f32_16x16x16bf16_1k(
            kf, qf[0], (f32x4){0.f,0.f,0.f,0.f}, 0, 0, 0);
        f32x4 s1 = __builtin_amdgcn_mfma_f32_16x16x16bf16_1k(
            kf, qf[1], (f32x4){0.f,0.f,0.f,0.f}, 0, 0, 0);
        #pragma unroll
        for (int r = 0; r < 4; ++r) {
            p[0][t * 4 + r] = s0[r];
            p[1][t * 4 + r] = s1[r];
        }
    }
#else
    #pragma unroll
    for (int t = 0; t < 4; ++t) {
        bf16x8 kf = (bf16x8){0,0,0,0,0,0,0,0};
        if (g < 2) {
            int mm = m0 + c + t * 16;
            if (MASK) mm = min(mm, L - 1);
            kf = *(const bf16x8*)(kb + (size_t)mm * 16 + g * 8);
        }
        f32x4 s0 = __builtin_amdgcn_mfma_f32_16x16x32_bf16(
            kf, qf[0], (f32x4){0.f,0.f,0.f,0.f}, 0, 0, 0);
        f32x4 s1 = __builtin_amdgcn_mfma_f32_16x16x32_bf16(
            kf, qf[1], (f32x4){0.f,0.f,0.f,0.f}, 0, 0, 0);
        #pragma unroll
        for (int r = 0; r < 4; ++r) {
            p[0][t * 4 + r] = s0[r];
            p[1][t * 4 + r] = s1[r];
        }
    }
#endif

    #pragma unroll
    for (int ch = 0; ch < 2; ++ch) {
        float tmax = -1e30f;
        #pragma unroll
        for (int t = 0; t < 4; ++t) {
            #pragma unroll
            for (int r = 0; r < 4; ++r) {
                float v = p[ch][t * 4 + r];
                if (MASK) {
                    int m = m0 + t * 16 + g * 4 + r;
                    if (m >= L) v = -1e30f;
                    p[ch][t * 4 + r] = v;
                }
                tmax = fmaxf(tmax, v);
            }
        }
        tmax = fmaxf(tmax, __shfl_xor(tmax, 16, 64));
        tmax = fmaxf(tmax, __shfl_xor(tmax, 32, 64));
        if (!__all(tmax <= mrun[ch])) {
            float mnew = fmaxf(mrun[ch], tmax);
            float corr = EXP2(mrun[ch] - mnew);
            srun[ch] *= corr;
            #pragma unroll
            for (int r = 0; r < 4; ++r) acc[ch][r] *= corr;
            mrun[ch] = mnew;
        }
        float ps0 = 0.f, ps1 = 0.f, ps2 = 0.f, ps3 = 0.f;
        #pragma unroll
        for (int t = 0; t < 4; ++t) {
            p[ch][t * 4 + 0] = EXP2(p[ch][t * 4 + 0] - mrun[ch]); ps0 += p[ch][t * 4 + 0];
            p[ch][t * 4 + 1] = EXP2(p[ch][t * 4 + 1] - mrun[ch]); ps1 += p[ch][t * 4 + 1];
            p[ch][t * 4 + 2] = EXP2(p[ch][t * 4 + 2] - mrun[ch]); ps2 += p[ch][t * 4 + 2];
            p[ch][t * 4 + 3] = EXP2(p[ch][t * 4 + 3] - mrun[ch]); ps3 += p[ch][t * 4 + 3];
        }
        srun[ch] += (ps0 + ps1) + (ps2 + ps3);
    }

#ifdef HAVE_MFMA16
    #pragma unroll
    for (int t = 0; t < 4; ++t) {
        bf16x4 vf = *(const bf16x4*)(vb + m0 + t * 16 + g * 4);           // shared
        bf16x4 pb0, pb1;
        #pragma unroll
        for (int j = 0; j < 4; ++j) {
            pb0[j] = (short)f2bf(p[0][t * 4 + j]);
            pb1[j] = (short)f2bf(p[1][t * 4 + j]);
        }
        acc[0] = __builtin_amdgcn_mfma_f32_16x16x16bf16_1k(vf, pb0, acc[0], 0, 0, 0);
        acc[1] = __builtin_amdgcn_mfma_f32_16x16x16bf16_1k(vf, pb1, acc[1], 0, 0, 0);
    }
#else
    int hi = g >> 1;
    #pragma unroll
    for (int H = 0; H < 2; ++H) {
        bf16x8 vf = *(const bf16x8*)(vb + m0 + H * 32 + g * 8);           // shared
        #pragma unroll
        for (int ch = 0; ch < 2; ++ch) {
            bf16x8 pb;
            #pragma unroll
            for (int j = 0; j < 8; ++j) {
                int srcLane = (((2 * g + (j >> 2)) & 3) << 4) | c;
                float v1 = __shfl(p[ch][(H * 2) * 4 + (j & 3)], srcLane, 64);
                float v2 = __shfl(p[ch][(H * 2 + 1) * 4 + (j & 3)], srcLane, 64);
                pb[j] = (short)f2bf(hi ? v2 : v1);
            }
            acc[ch] = __builtin_amdgcn_mfma_f32_16x16x32_bf16(vf, pb, acc[ch], 0, 0, 0);
        }
    }
#endif
}

// ---------------- MFMA flash attention: 2 query-chains per wave ---------------
template<int L, int LP>
__device__ __forceinline__ void attn_body(
    const unsigned short* __restrict__ Q, const unsigned short* __restrict__ Kt,
    const unsigned short* __restrict__ V, unsigned short* __restrict__ O,
    int lblk, int bh)
{
    constexpr int NFULL = L / 64;
    constexpr int TAIL  = L % 64;

    int tid  = threadIdx.x;
    int lane = tid & 63;
    int wv   = tid >> 6;
    int c    = lane & 15;
    int g    = lane >> 4;
    int b = bh >> 2, h = bh & 3;
    const unsigned short* qb = Q + (size_t)(b * 64 + h * 16) * L;
    const unsigned short* kb = Kt + (size_t)bh * L * 16;
    const unsigned short* vb = V + (size_t)(b * 64 + h * 16) * LP + (size_t)c * LP;
    unsigned short* ob = O + (size_t)(b * 64 + h * 16) * L;

    int lbase = lblk * 128 + wv * 16 + c;
    int l[2] = {lbase, lbase + 64};
    bool lval[2];
    int lc[2];
    #pragma unroll
    for (int ch = 0; ch < 2; ++ch) {
        lval[ch] = (l[ch] < L);
        lc[ch] = lval[ch] ? l[ch] : (L - 1);
    }

    f32x4 acc[2];
    float mrun[2], srun[2];
    #pragma unroll
    for (int ch = 0; ch < 2; ++ch) {
        acc[ch] = (f32x4){0.f, 0.f, 0.f, 0.f};
        mrun[ch] = -1e30f; srun[ch] = 0.f;
    }

#ifdef HAVE_MFMA16
    bf16x4 qf[2];
    #pragma unroll
    for (int ch = 0; ch < 2; ++ch)
        #pragma unroll
        for (int j = 0; j < 4; ++j) qf[ch][j] = (short)qb[(g * 4 + j) * L + lc[ch]];
#else
    bf16x8 qf[2];
    #pragma unroll
    for (int ch = 0; ch < 2; ++ch) {
        qf[ch] = (bf16x8){0,0,0,0,0,0,0,0};
        if (g < 2) {
            #pragma unroll
            for (int j = 0; j < 8; ++j) qf[ch][j] = (short)qb[(g * 8 + j) * L + lc[ch]];
        }
    }
#endif

    for (int mt = 0; mt < NFULL; ++mt)
        attn_tile<L, LP, false>(mt * 64, kb, vb, c, g, qf, acc, mrun, srun);
    if (TAIL > 0)
        attn_tile<L, LP, true>(NFULL * 64, kb, vb, c, g, qf, acc, mrun, srun);

    #pragma unroll
    for (int ch = 0; ch < 2; ++ch) {
        float stot = srun[ch];
        stot += __shfl_xor(stot, 16, 64);
        stot += __shfl_xor(stot, 32, 64);
        float inv = 1.f / stot;
        if (lval[ch]) {
            #pragma unroll
            for (int r = 0; r < 4; ++r)
                ob[(size_t)(g * 4 + r) * L + l[ch]] = f2bf(acc[ch][r] * inv);
        }
    }
}

__global__ __launch_bounds__(256) void attn_c_k(
    const unsigned short* __restrict__ Qa, const unsigned short* __restrict__ Ka,
    const unsigned short* __restrict__ Va, unsigned short* __restrict__ Oa)
{
    int bid = blockIdx.x;
    if (bid < 640) {                               // chunk0: 5 lblk x 128 bh
        attn_body<625, 632>(Qa, Ka, Va, Oa, bid % 5, bid / 5);
    } else if (bid < 1664) {                       // chunk1: 2 lblk x 512 bh
        int k = bid - 640;
        attn_body<256, 256>(Qa + 1280000, Ka + 1280000, Va + 1294336,
                            Oa + 1280000, k % 2, k / 2);
    } else {                                       // chunk2: 2 lblk x 1152 bh
        int k = bid - 1664;
        attn_body<144, 144>(Qa + 3377152, Ka + 3377152, Va + 3391488,
                            Oa + 3377152, k % 2, k / 2);
    }
}

// ---------------- proj + residual body (templated), bf16 O input --------------
template<int L, int NPIX>
__device__ __forceinline__ void proj_body(
    unsigned short (*lds)[72],
    const unsigned short* __restrict__ O, const float* __restrict__ U,
    const float* __restrict__ pw, float* __restrict__ A, int bid)
{
    int tid  = threadIdx.x;
    int lane = tid & 63;
    int wv   = tid >> 6;
    int c    = lane & 15;
    int g8   = (lane >> 4) * 8;
    int q0   = bid * 64;

    int sp = tid >> 2;
    int sk = (tid & 3) * 8;
    int qc = min(q0 + sp, NPIX - 1);
    int b  = qc / L, p = qc % L;
    const unsigned short* ob = O + (size_t)b * 64 * L + p;

    bf16x8 b0, b1;
    #pragma unroll
    for (int j = 0; j < 8; ++j) {
        b0[j] = (short)ob[(size_t)(sk + j) * L];
        b1[j] = (short)ob[(size_t)(32 + sk + j) * L];
    }
    __syncthreads();
    *(bf16x8*)(&lds[sp][sk])      = b0;
    *(bf16x8*)(&lds[sp][32 + sk]) = b1;
    __syncthreads();

    f32x4 acc[4];
    #pragma unroll
    for (int f = 0; f < 4; ++f) acc[f] = (f32x4){0.f, 0.f, 0.f, 0.f};

    const float* arow = pw + (size_t)(wv * 16 + c) * 64;
    #pragma unroll
    for (int h = 0; h < 2; ++h) {
        bf16x8 a;
        const float* ap = arow + h * 32 + g8;
        #pragma unroll
        for (int j = 0; j < 8; ++j) a[j] = (short)f2bf(ap[j]);
        #pragma unroll
        for (int f = 0; f < 4; ++f) {
            bf16x8 bfr = *(const bf16x8*)(&lds[f * 16 + c][h * 32 + g8]);
            acc[f] = __builtin_amdgcn_mfma_f32_16x16x32_bf16(a, bfr, acc[f], 0, 0, 0);
        }
    }

    #pragma unroll
    for (int f = 0; f < 4; ++f) {
        int qq = q0 + f * 16 + c;
        if (qq < NPIX) {
            int bo = qq / L, po = qq % L;
            #pragma unroll
            for (int r = 0; r < 4; ++r) {
                int co = wv * 16 + (lane >> 4) * 4 + r;
                size_t oi = (size_t)(bo * 64 + co) * L + po;
                A[oi] = acc[f][r] + U[oi];
            }
        }
    }
}

__global__ __launch_bounds__(256) void proj_c_k(
    const unsigned short* __restrict__ Oa, const float* __restrict__ Uall,
    const float* __restrict__ pw, float* __restrict__ Aa)
{
    __shared__ unsigned short lds[64][72];
    int bid = blockIdx.x;
    if (bid < 313)
        proj_body<625, 20000>(lds, Oa, Uall, pw, Aa, bid);
    else if (bid < 825)
        proj_body<256, 32768>(lds, Oa + 1280000, Uall + 1280000, pw, Aa + 1280000, bid - 313);
    else
        proj_body<144, 41472>(lds, Oa + 3377152, Uall + 3377152, pw, Aa + 3377152, bid - 825);
}

// ---------------- padU body (templated) ---------------------------------------
template<int KH, int PW, int L>
__device__ __forceinline__ void padU_body(
    const float* __restrict__ U, unsigned short* __restrict__ Up, int idx)
{
    int pp = idx % (PW * PW);
    int b  = idx / (PW * PW);
    int xx = pp % PW, yy = pp / PW;
    bool inter = (xx >= 1 && xx <= KH && yy >= 1 && yy <= KH);
    const float* up = U + (size_t)b * 64 * L + (yy - 1) * KH + (xx - 1);
    unsigned short vals[64];
    #pragma unroll
    for (int j = 0; j < 64; ++j) vals[j] = inter ? f2bf(up[(size_t)j * L]) : 0;
    unsigned short* op = Up + (size_t)idx * 64;
    #pragma unroll
    for (int v = 0; v < 8; ++v) {
        bf16x8 pack;
        #pragma unroll
        for (int j = 0; j < 8; ++j) pack[j] = (short)vals[v * 8 + j];
        *(bf16x8*)(op + v * 8) = pack;
    }
}

__global__ __launch_bounds__(256) void padU_c_k(
    const float* __restrict__ Uall, unsigned short* __restrict__ Upa)
{
    int idx = blockIdx.x * 256 + threadIdx.x;
    if (idx < 23328)        padU_body<25, 27, 625>(Uall,            Upa,            idx);
    else if (idx < 64800)   padU_body<16, 18, 256>(Uall + 1280000,  Upa + 1492992,  idx - 23328);
    else if (idx < 121248)  padU_body<12, 14, 144>(Uall + 3377152,  Upa + 4147200,  idx - 64800);
}

// ---------------- posconv body (templated), LDS dbuf --------------------------
template<int L, int PW, int KH, int NPIX>
__device__ __forceinline__ void posconv_body(
    unsigned short (*lds)[64][72],
    const unsigned short* __restrict__ Up, const unsigned short* __restrict__ Wb,
    const float* __restrict__ g, const float* __restrict__ bb,
    float* __restrict__ A, int bid)
{
    int tid  = threadIdx.x;
    int lane = tid & 63;
    int wv   = tid >> 6;
    int c    = lane & 15;
    int g8   = (lane >> 4) * 8;
    int p0   = bid * 64;

    int sp = tid >> 2;
    int sk = (tid & 3) * 8;
    int qq0 = p0 + sp;
    int po = 0;
    if (qq0 < NPIX) {
        int b = qq0 / L, p = qq0 % L;
        po = b * PW * PW + (p / KH) * PW + (p % KH);
    }

    const unsigned short* arow = Wb + (size_t)(wv * 16 + c) * KPOS_;

    f32x4 acc[4];
    #pragma unroll
    for (int f = 0; f < 4; ++f) acc[f] = (f32x4){0.f, 0.f, 0.f, 0.f};

    const int NT = KPOS_ / 64;                // 9

    bf16x8 b0, b1, a0, a1;
    {
        const unsigned short* bp = Up + ((size_t)po << 6);
        b0 = *(const bf16x8*)(bp + sk);
        b1 = *(const bf16x8*)(bp + 32 + sk);
        *(bf16x8*)(&lds[0][sp][sk])      = b0;
        *(bf16x8*)(&lds[0][sp][32 + sk]) = b1;
    }
    {
        const unsigned short* bp = Up + ((size_t)(po + 1) << 6);  // tap 1
        b0 = *(const bf16x8*)(bp + sk);
        b1 = *(const bf16x8*)(bp + 32 + sk);
    }
    a0 = *(const bf16x8*)(arow + g8);
    a1 = *(const bf16x8*)(arow + 32 + g8);

    for (int t = 0; t < NT; ++t) {
        __syncthreads();
        bf16x8 bf0[4], bf1[4];
        #pragma unroll
        for (int f = 0; f < 4; ++f) {
            bf0[f] = *(const bf16x8*)(&lds[t & 1][f * 16 + c][g8]);
            bf1[f] = *(const bf16x8*)(&lds[t & 1][f * 16 + c][32 + g8]);
        }
        if (t + 1 < NT) {
            *(bf16x8*)(&lds[(t + 1) & 1][sp][sk])      = b0;
            *(bf16x8*)(&lds[(t + 1) & 1][sp][32 + sk]) = b1;
            if (t + 2 < NT) {
                int tap = t + 2;
                int toff = (tap / 3) * PW + (tap % 3);
                const unsigned short* bp = Up + ((size_t)(po + toff) << 6);
                b0 = *(const bf16x8*)(bp + sk);
                b1 = *(const bf16x8*)(bp + 32 + sk);
            }
        }
        bf16x8 a0n, a1n;
        if (t + 1 < NT) {
            a0n = *(const bf16x8*)(arow + (t + 1) * 64 + g8);
            a1n = *(const bf16x8*)(arow + (t + 1) * 64 + 32 + g8);
        }
        #pragma unroll
        for (int f = 0; f < 4; ++f) {
            acc[f] = __builtin_amdgcn_mfma_f32_16x16x32_bf16(a0, bf0[f], acc[f], 0, 0, 0);
            acc[f] = __builtin_amdgcn_mfma_f32_16x16x32_bf16(a1, bf1[f], acc[f], 0, 0, 0);
        }
        a0 = a0n; a1 = a1n;
    }

    #pragma unroll
    for (int f = 0; f < 4; ++f) {
        int q = p0 + f * 16 + c;
        if (q < NPIX) {
            int b = q / L, p = q % L;
            #pragma unroll
            for (int r = 0; r < 4; ++r) {
                int co = wv * 16 + (lane >> 4) * 4 + r;
                A[(size_t)(b * 64 + co) * L + p] += acc[f][r] * bn_scale(g[co]) + bb[co];
            }
        }
    }
}

__global__ __launch_bounds__(256) void posconv_c_k(
    const unsigned short* __restrict__ Upa, const unsigned short* __restrict__ Wb,
    const float* __restrict__ g, const float* __restrict__ bb,
    float* __restrict__ Aa)
{
    __shared__ unsigned short lds[2][64][72];
    int bid = blockIdx.x;
    if (bid < 313)
        posconv_body<625, 27, 25, 20000>(lds, Upa, Wb, g, bb, Aa, bid);
    else if (bid < 825)
        posconv_body<256, 18, 16, 32768>(lds, Upa + 1492992, Wb, g, bb, Aa + 1280000, bid - 313);
    else
        posconv_body<144, 14, 12, 41472>(lds, Upa + 4147200, Wb, g, bb, Aa + 3377152, bid - 825);
}

// ---------------- fold body: writes conv2's NHWC bf16 input directly ----------
template<int NW, int SH, int KH>
__device__ __forceinline__ void fold_body(
    const float* __restrict__ A, unsigned short* __restrict__ Xb, int idx, int cidx)
{
    int w  = idx % HW_;
    int h  = (idx / HW_) % HW_;
    int cb = (idx / PIX_) % CB_;
    int n  = idx / (PIX_ * CB_);
    int numh = h - KH + 1;
    int ilo = numh > 0 ? (numh + SH - 1) / SH : 0;
    int ihi = min(NW - 1, h / SH);
    int numw = w - KH + 1;
    int jlo = numw > 0 ? (numw + SH - 1) / SH : 0;
    int jhi = min(NW - 1, w / SH);
    float sum = 0.f;
    for (int i = ilo; i <= ihi; ++i) {
        int r = h - i * SH;
        for (int j = jlo; j <= jhi; ++j) {
            int c = w - j * SH;
            int f = ((((n * CB_ + cb) * KH + r) * KH + c) * NW + i) * NW + j;
            sum += A[f];
        }
    }
    float cnt = (float)((ihi - ilo + 1) * (jhi - jlo + 1));
    Xb[((size_t)n * PADPIX_ + (h + 1) * PADW_ + (w + 1)) * 192 + cidx * CB_ + cb]
        = f2bf(sum / cnt);
}

__global__ __launch_bounds__(256) void fold_c_k(
    const float* __restrict__ Aa, unsigned short* __restrict__ Xb)
{
    int idx = blockIdx.x * 256 + threadIdx.x;
    if (idx < 1280000)       fold_body<4, 25, 25>(Aa,            Xb, idx,            0);
    else if (idx < 2560000)  fold_body<8, 12, 16>(Aa + 1280000,  Xb, idx - 1280000,  1);
    else if (idx < 3840000)  fold_body<12, 8, 12>(Aa + 3377152,  Xb, idx - 2560000,  2);
}

// ---------------- prep: zero pad ring of NHWC buffer --------------------------
__global__ __launch_bounds__(256) void ring_zero_k(unsigned short* __restrict__ Xb)
{
    int idx = blockIdx.x * 256 + threadIdx.x;
    if (idx >= N_ * 404 * 192) return;
    int cc = idx % 192;
    int rp = (idx / 192) % 404;
    int n  = idx / (192 * 404);
    int yy, xx;
    if (rp < 102)      { yy = 0;            xx = rp; }
    else if (rp < 204) { yy = 101;          xx = rp - 102; }
    else if (rp < 304) { yy = rp - 204 + 1; xx = 0; }
    else               { yy = rp - 304 + 1; xx = 101; }
    Xb[((size_t)n * PADPIX_ + yy * PADW_ + xx) * 192 + cc] = 0;
}

// ---------------- 3x3 conv implicit GEMM, NHWC bf16, XCD swizzle + LDS dbuf ---
#define NB3_ (157*3*2)
template<bool RES, bool TOXB>
__global__ __launch_bounds__(256) void conv3x3_mfma_k(
    const unsigned short* __restrict__ Xp,
    const unsigned short* __restrict__ Wb,
    const float* __restrict__ g, const float* __restrict__ bb,
    const float* __restrict__ res, float* __restrict__ out,
    unsigned short* __restrict__ xout)
{
    __shared__ unsigned short lds[2][64][72];
    int tid  = threadIdx.x;
    int lane = tid & 63;
    int wv   = tid >> 6;
    int c    = lane & 15;
    int g8   = (lane >> 4) * 8;

    const int q = NB3_ / 8, r = NB3_ % 8;
    int gid  = blockIdx.x;
    int xcd  = gid % 8, slot = gid / 8;
    int wgid = (xcd < r) ? xcd * (q + 1) + slot
                         : r * (q + 1) + (xcd - r) * q + slot;
    int co0  = (wgid % 3) * 64;
    int rest = wgid / 3;
    int p0   = (rest % 157) * 64;
    int n    = rest / 157;

    const unsigned short* Xn = Xp + (size_t)n * PADPIX_ * 192;

    int sp = tid >> 2;
    int sk = (tid & 3) * 8;
    int pix = p0 + sp;
    int po = (pix < PIX_) ? (pix / HW_) * PADW_ + (pix % HW_) : 0;

    const unsigned short* arow = Wb + (size_t)(co0 + wv * 16 + c) * KTOT_;

    f32x4 acc[4];
    #pragma unroll
    for (int f = 0; f < 4; ++f) acc[f] = (f32x4){0.f, 0.f, 0.f, 0.f};

    const int NT = KTOT_ / 64;

    bf16x8 b0, b1, a0, a1;
    {
        const unsigned short* bp = Xn + (size_t)po * 192;
        b0 = *(const bf16x8*)(bp + sk);
        b1 = *(const bf16x8*)(bp + 32 + sk);
        *(bf16x8*)(&lds[0][sp][sk])      = b0;
        *(bf16x8*)(&lds[0][sp][32 + sk]) = b1;
    }
    {
        const unsigned short* bp = Xn + (size_t)po * 192 + 64;
        b0 = *(const bf16x8*)(bp + sk);
        b1 = *(const bf16x8*)(bp + 32 + sk);
    }
    a0 = *(const bf16x8*)(arow + g8);
    a1 = *(const bf16x8*)(arow + 32 + g8);

    for (int t = 0; t < NT; ++t) {
        __syncthreads();
        bf16x8 bf0[4], bf1[4];
        #pragma unroll
        for (int f = 0; f < 4; ++f) {
            bf0[f] = *(const bf16x8*)(&lds[t & 1][f * 16 + c][g8]);
            bf1[f] = *(const bf16x8*)(&lds[t & 1][f * 16 + c][32 + g8]);
        }
        if (t + 1 < NT) {
            *(bf16x8*)(&lds[(t + 1) & 1][sp][sk])      = b0;
            *(bf16x8*)(&lds[(t + 1) & 1][sp][32 + sk]) = b1;
            if (t + 2 < NT) {
                int k2 = (t + 2) * 64;
                int tap = k2 / 192;
                int ci0 = k2 - tap * 192;
                int toff = (tap / 3) * PADW_ + (tap % 3);
                const unsigned short* bp = Xn + (size_t)(po + toff) * 192 + ci0;
                b0 = *(const bf16x8*)(bp + sk);
                b1 = *(const bf16x8*)(bp + 32 + sk);
            }
        }
        bf16x8 a0n, a1n;
        if (t + 1 < NT) {
            a0n = *(const bf16x8*)(arow + (t + 1) * 64 + g8);
            a1n = *(const bf16x8*)(arow + (t + 1) * 64 + 32 + g8);
        }
        #pragma unroll
        for (int f = 0; f < 4; ++f) {
            acc[f] = __builtin_amdgcn_mfma_f32_16x16x32_bf16(a0, bf0[f], acc[f], 0, 0, 0);
            acc[f] = __builtin_amdgcn_mfma_f32_16x16x32_bf16(a1, bf1[f], acc[f], 0, 0, 0);
        }
        a0 = a0n; a1 = a1n;
    }

    #pragma unroll
    for (int f = 0; f < 4; ++f) {
        int p = p0 + f * 16 + c;
        if (p < PIX_) {
            if (TOXB) {
                int py = p / HW_, px = p % HW_;
                unsigned short* o = xout +
                    ((size_t)n * PADPIX_ + (py + 1) * PADW_ + (px + 1)) * 192 +
                    co0 + wv * 16 + (lane >> 4) * 4;
                ushort4 pk;
                #pragma unroll
                for (int r2 = 0; r2 < 4; ++r2) {
                    int co = co0 + wv * 16 + (lane >> 4) * 4 + r2;
                    float v = acc[f][r2] * bn_scale(g[co]) + bb[co];
                    if (RES) v += res[(size_t)(n * C_ + co) * PIX_ + p];
                    ((unsigned short*)&pk)[r2] = f2bf(v);
                }
                *(ushort4*)o = pk;
            } else {
                #pragma unroll
                for (int r2 = 0; r2 < 4; ++r2) {
                    int co = co0 + wv * 16 + (lane >> 4) * 4 + r2;
                    float v = acc[f][r2] * bn_scale(g[co]) + bb[co];
                    if (RES) v += res[(size_t)(n * C_ + co) * PIX_ + p];
                    out[(size_t)(n * C_ + co) * PIX_ + p] = v;
                }
            }
        }
    }
}

extern "C" void kernel_launch(void* const* d_in, const int* in_sizes, int n_in,
                              void* d_out, int out_size, void* d_ws, size_t ws_size,
                              hipStream_t stream) {
    const float* x       = (const float*)d_in[0];
    const float* conv1_w = (const float*)d_in[1];
    const float* bn1_g   = (const float*)d_in[2];
    const float* bn1_b   = (const float*)d_in[3];
    const float* conv2_w = (const float*)d_in[4];
    const float* bn2_g   = (const float*)d_in[5];
    const float* bn2_b   = (const float*)d_in[6];
    const float* conv3_w = (const float*)d_in[7];
    const float* bn3_g   = (const float*)d_in[8];
    const float* bn3_b   = (const float*)d_in[9];
    const float* pos_w   = (const float*)d_in[10];
    const float* bnp_g   = (const float*)d_in[11];
    const float* bnp_b   = (const float*)d_in[12];
    const float* q_w     = (const float*)d_in[13];
    const float* k_w     = (const float*)d_in[14];
    const float* v_w     = (const float*)d_in[15];
    const float* proj_w  = (const float*)d_in[16];

    float* ws = (float*)d_ws;
    float* x1   = ws;                                        // 3,840,000
    float* cat  = ws + 3840000;                              // (dead, kept for layout)
    unsigned short* Xc    = (unsigned short*)(ws + 7680000); // 3,840,000 sh
    float* Uall = ws + 9600000;                              // 6,031,360
    unsigned short* Oall  = (unsigned short*)(ws + 15640000);// 6,031,360 sh
    float* Aall = ws + 21680000;                             // 6,031,360
    unsigned short* Qall  = (unsigned short*)(ws + 27720000);// 6,031,360 sh
    unsigned short* Ktall = (unsigned short*)(ws + 30740000);
    unsigned short* Vall  = (unsigned short*)(ws + 33760000);// 6,045,696 sh
    unsigned short* Upall = (unsigned short*)(ws + 36790000);// 7,759,872 sh
    unsigned short* pwb   = (unsigned short*)(ws + 40670000);
    unsigned short* w2b   = (unsigned short*)(ws + 40690000);
    unsigned short* w3b   = (unsigned short*)(ws + 40856000);
    unsigned short* Xb    = (unsigned short*)(ws + 41022000);// 3,995,136 sh
    unsigned short* Xb2   = (unsigned short*)(ws + 43020000);
    (void)cat;

    x_nhwc_k<<<(N_ * 4 * PIX_ + 255) / 256, 256, 0, stream>>>(x, Xc);
    conv1x1_mfma_k<<<dim3(157, 3, 2), 256, 0, stream>>>(Xc, conv1_w, bn1_g, bn1_b, x1);
    wcvt_all_k<<<(700416 + 255) / 256, 256, 0, stream>>>(pos_w, conv2_w, conv3_w, pwb, w2b, w3b);

    gather_c_k<<<(6031360 + 255) / 256, 256, 0, stream>>>(x1, Uall);
    qkv_c_k<<<1473, 256, 0, stream>>>(Uall, q_w, k_w, v_w, Qall, Ktall, Vall);
    attn_c_k<<<2688 + 1280, 256, 0, stream>>>(Qall, Ktall, Vall, Oall);
    proj_c_k<<<1473, 256, 0, stream>>>(Oall, Uall, proj_w, Aall);
    padU_c_k<<<(121248 + 255) / 256, 256, 0, stream>>>(Uall, Upall);
    posconv_c_k<<<1473, 256, 0, stream>>>(Upall, pwb, bnp_g, bnp_b, Aall);

    ring_zero_k<<<(N_ * 404 * 192 + 255) / 256, 256, 0, stream>>>(Xb);
    fold_c_k<<<(3840000 + 255) / 256, 256, 0, stream>>>(Aall, Xb);

    ring_zero_k<<<(N_ * 404 * 192 + 255) / 256, 256, 0, stream>>>(Xb2);
    conv3x3_mfma_k<true, true><<<NB3_, 256, 0, stream>>>(
        Xb, w2b, bn2_g, bn2_b, x1, nullptr, Xb2);
    conv3x3_mfma_k<false, false><<<NB3_, 256, 0, stream>>>(
        Xb2, w3b, bn3_g, bn3_b, nullptr, (float*)d_out, nullptr);
}

// Round 23
// 266.304 us; speedup vs baseline: 1.1080x; 1.1080x over previous
//
#include <hip/hip_runtime.h>
#include <hip/hip_bf16.h>

#define N_ 2
#define C_ 192
#define CB_ 64
#define HW_ 100
#define PIX_ (HW_*HW_)
#define PADW_ 102
#define PADPIX_ (PADW_*PADW_)
#define KTOT_ 1728
#define KPOS_ 576
#define QSCALE_ 0.3606737602222409f   // 0.25 * log2(e)

typedef __attribute__((ext_vector_type(8))) short bf16x8;
typedef __attribute__((ext_vector_type(4))) short bf16x4;
typedef __attribute__((ext_vector_type(4))) float f32x4;

#if defined(__has_builtin)
#if __has_builtin(__builtin_amdgcn_mfma_f32_16x16x16bf16_1k)
#define HAVE_MFMA16 1
#endif
#if __has_builtin(__builtin_amdgcn_exp2f)
#define EXP2(x) __builtin_amdgcn_exp2f(x)
#endif
#endif
#ifndef EXP2
#define EXP2(x) exp2f(x)
#endif

static __device__ __forceinline__ float bn_scale(float g) {
    return g * rsqrtf(1.0f + 1e-5f);
}

static __device__ __forceinline__ unsigned short f2bf(float v) {
    __hip_bfloat16 h = __float2bfloat16(v);
    return *(unsigned short*)&h;
}

static __device__ __forceinline__ float bf2f(unsigned short u) {
    unsigned int v = ((unsigned int)u) << 16;
    return __uint_as_float(v);
}

// ---------------- prep: fp32 NCHW x -> bf16 channel-last [n][PIX][192] --------
__global__ __launch_bounds__(256) void x_nhwc_k(
    const float* __restrict__ in, unsigned short* __restrict__ out)
{
    int idx = blockIdx.x * 256 + threadIdx.x;
    if (idx >= N_ * 4 * PIX_) return;
    int p     = idx % PIX_;
    int chunk = (idx / PIX_) & 3;
    int n     = idx / (PIX_ * 4);
    int c0 = chunk * 48;
    const float* ip = in + ((size_t)n * C_ + c0) * PIX_ + p;
    unsigned short vals[48];
    #pragma unroll
    for (int j = 0; j < 48; ++j) vals[j] = f2bf(ip[(size_t)j * PIX_]);
    unsigned short* op = out + ((size_t)n * PIX_ + p) * 192 + c0;
    #pragma unroll
    for (int v = 0; v < 6; ++v) {
        bf16x8 pack;
        #pragma unroll
        for (int j = 0; j < 8; ++j) pack[j] = (short)vals[v * 8 + j];
        *(bf16x8*)(op + v * 8) = pack;
    }
}

// ---------------- conv1x1 + BN as GEMM, bf16 MFMA, NHWC input ----------------
__global__ __launch_bounds__(256) void conv1x1_mfma_k(
    const unsigned short* __restrict__ Xc,
    const float* __restrict__ w,
    const float* __restrict__ g, const float* __restrict__ bb,
    float* __restrict__ out)
{
    __shared__ unsigned short lds[64][72];
    int tid  = threadIdx.x;
    int lane = tid & 63;
    int wv   = tid >> 6;
    int c    = lane & 15;
    int g8   = (lane >> 4) * 8;
    int p0   = blockIdx.x * 64;
    int co0  = blockIdx.y * 64;
    int n    = blockIdx.z;

    int sp = tid >> 2;
    int sk = (tid & 3) * 8;
    int pc = min(p0 + sp, PIX_ - 1);
    const unsigned short* bp = Xc + ((size_t)n * PIX_ + pc) * 192;

    const float* arow = w + (size_t)(co0 + wv * 16 + c) * C_;

    f32x4 acc[4];
    #pragma unroll
    for (int f = 0; f < 4; ++f) acc[f] = (f32x4){0.f, 0.f, 0.f, 0.f};

    bf16x8 b0 = *(const bf16x8*)(bp + sk);
    bf16x8 b1 = *(const bf16x8*)(bp + 32 + sk);

    for (int k0 = 0; k0 < C_; k0 += 64) {
        __syncthreads();
        *(bf16x8*)(&lds[sp][sk])      = b0;
        *(bf16x8*)(&lds[sp][32 + sk]) = b1;
        __syncthreads();
        if (k0 + 64 < C_) {
            b0 = *(const bf16x8*)(bp + k0 + 64 + sk);
            b1 = *(const bf16x8*)(bp + k0 + 96 + sk);
        }
        #pragma unroll
        for (int h = 0; h < 2; ++h) {
            bf16x8 a;
            const float* ap = arow + k0 + h * 32 + g8;
            #pragma unroll
            for (int j = 0; j < 8; ++j) a[j] = (short)f2bf(ap[j]);
            #pragma unroll
            for (int f = 0; f < 4; ++f) {
                bf16x8 b = *(const bf16x8*)(&lds[f * 16 + c][h * 32 + g8]);
                acc[f] = __builtin_amdgcn_mfma_f32_16x16x32_bf16(a, b, acc[f], 0, 0, 0);
            }
        }
    }

    #pragma unroll
    for (int f = 0; f < 4; ++f) {
        int p = p0 + f * 16 + c;
        if (p < PIX_) {
            #pragma unroll
            for (int r = 0; r < 4; ++r) {
                int co = co0 + wv * 16 + (lane >> 4) * 4 + r;
                out[(size_t)(n * C_ + co) * PIX_ + p] = acc[f][r] * bn_scale(g[co]) + bb[co];
            }
        }
    }
}

// ---------------- combined weight converts (pos + conv2 + conv3) -------------
__global__ __launch_bounds__(256) void wcvt_all_k(
    const float* __restrict__ pw, const float* __restrict__ w2,
    const float* __restrict__ w3,
    unsigned short* __restrict__ pwb, unsigned short* __restrict__ w2b,
    unsigned short* __restrict__ w3b)
{
    int idx = blockIdx.x * 256 + threadIdx.x;
    const int S0 = CB_ * KPOS_;          // 36864
    const int S1 = S0 + C_ * KTOT_;      // 368640
    const int S2 = S1 + C_ * KTOT_;      // 700416
    if (idx < S0) {
        int t = idx % 9, ci = (idx / 9) % CB_, co = idx / (9 * CB_);
        pwb[(size_t)co * KPOS_ + t * CB_ + ci] = f2bf(pw[idx]);
    } else if (idx < S1) {
        int k = idx - S0;
        int t = k % 9, ci = (k / 9) % C_, co = k / (9 * C_);
        w2b[(size_t)co * KTOT_ + t * C_ + ci] = f2bf(w2[k]);
    } else if (idx < S2) {
        int k = idx - S1;
        int t = k % 9, ci = (k / 9) % C_, co = k / (9 * C_);
        w3b[(size_t)co * KTOT_ + t * C_ + ci] = f2bf(w3[k]);
    }
}

// ---------------- combined gather (all 3 chunks), bf16 output -----------------
template<int NW, int SH, int KH>
__device__ __forceinline__ void gather_body(
    const float* __restrict__ x1, unsigned short* __restrict__ U, int f, int cidx)
{
    int t = f;
    int j = t % NW; t /= NW;
    int i = t % NW; t /= NW;
    int c = t % KH; t /= KH;
    int r = t % KH; t /= KH;
    int cb = t % CB_;
    int n  = t / CB_;
    int hh = i * SH + r;
    int ww = j * SH + c;
    U[f] = f2bf(x1[((n * C_ + cidx * CB_ + cb) * HW_ + hh) * HW_ + ww]);
}

__global__ __launch_bounds__(256) void gather_c_k(
    const float* __restrict__ x1, unsigned short* __restrict__ Uall)
{
    int gid = blockIdx.x * 256 + threadIdx.x;
    if (gid < 1280000)       gather_body<4, 25, 25>(x1, Uall,            gid,            0);
    else if (gid < 3377152)  gather_body<8, 12, 16>(x1, Uall + 1280000,  gid - 1280000,  1);
    else if (gid < 6031360)  gather_body<12, 8, 12>(x1, Uall + 3377152,  gid - 3377152,  2);
}

// ---------------- fused q/k/v GEMM body (templated L), bf16 U -----------------
template<int L, int LP, int NPIX>
__device__ __forceinline__ void qkv_body(
    unsigned short (*lds)[72],
    const unsigned short* __restrict__ U,
    const float* __restrict__ qw, const float* __restrict__ kw,
    const float* __restrict__ vw,
    unsigned short* __restrict__ Q, unsigned short* __restrict__ Kt,
    unsigned short* __restrict__ V, int bid)
{
    int tid  = threadIdx.x;
    int lane = tid & 63;
    int wv   = tid >> 6;
    int c    = lane & 15;
    int g8   = (lane >> 4) * 8;
    int q0   = bid * 64;

    int sp = tid >> 2;
    int sk = (tid & 3) * 8;
    int qc = min(q0 + sp, NPIX - 1);
    int b  = qc / L, p = qc % L;
    const unsigned short* ub = U + (size_t)b * 64 * L + p;

    bf16x8 b0, b1;
    #pragma unroll
    for (int j = 0; j < 8; ++j) {
        b0[j] = (short)ub[(size_t)(sk + j) * L];
        b1[j] = (short)ub[(size_t)(32 + sk + j) * L];
    }
    __syncthreads();
    *(bf16x8*)(&lds[sp][sk])      = b0;
    *(bf16x8*)(&lds[sp][32 + sk]) = b1;
    __syncthreads();

    f32x4 acc[3][4];
    #pragma unroll
    for (int s = 0; s < 3; ++s)
        #pragma unroll
        for (int f = 0; f < 4; ++f) acc[s][f] = (f32x4){0.f, 0.f, 0.f, 0.f};

    const float* wbase[3] = {qw, kw, vw};
    #pragma unroll
    for (int s = 0; s < 3; ++s) {
        const float* arow = wbase[s] + (size_t)(wv * 16 + c) * 64;
        #pragma unroll
        for (int h = 0; h < 2; ++h) {
            bf16x8 a;
            const float* ap = arow + h * 32 + g8;
            #pragma unroll
            for (int j = 0; j < 8; ++j) a[j] = (short)f2bf(ap[j]);
            #pragma unroll
            for (int f = 0; f < 4; ++f) {
                bf16x8 bfr = *(const bf16x8*)(&lds[f * 16 + c][h * 32 + g8]);
                acc[s][f] = __builtin_amdgcn_mfma_f32_16x16x32_bf16(a, bfr, acc[s][f], 0, 0, 0);
            }
        }
    }

    #pragma unroll
    for (int f = 0; f < 4; ++f) {
        int qq = q0 + f * 16 + c;
        if (qq < NPIX) {
            int bo = qq / L, po = qq % L;
            #pragma unroll
            for (int r = 0; r < 4; ++r) {
                int co = wv * 16 + (lane >> 4) * 4 + r;
                Q[(size_t)(bo * 64 + co) * L + po] = f2bf(acc[0][f][r] * QSCALE_);
                Kt[((size_t)(bo * 4 + wv) * L + po) * 16 + ((lane >> 4) * 4 + r)] = f2bf(acc[1][f][r]);
                V[(size_t)(bo * 64 + co) * LP + po] = f2bf(acc[2][f][r]);
            }
        }
    }
}

__global__ __launch_bounds__(256) void qkv_c_k(
    const unsigned short* __restrict__ Uall,
    const float* __restrict__ qw, const float* __restrict__ kw,
    const float* __restrict__ vw,
    unsigned short* __restrict__ Qa, unsigned short* __restrict__ Ka,
    unsigned short* __restrict__ Va)
{
    __shared__ unsigned short lds[64][72];
    int bid = blockIdx.x;
    if (bid < 313)
        qkv_body<625, 632, 20000>(lds, Uall, qw, kw, vw, Qa, Ka, Va, bid);
    else if (bid < 825)
        qkv_body<256, 256, 32768>(lds, Uall + 1280000, qw, kw, vw,
                                  Qa + 1280000, Ka + 1280000, Va + 1294336, bid - 313);
    else
        qkv_body<144, 144, 41472>(lds, Uall + 3377152, qw, kw, vw,
                                  Qa + 3377152, Ka + 3377152, Va + 3391488, bid - 825);
}

// ---------------- attention tile body (MASK only for the tail tile) -----------
template<int L, int LP, bool MASK>
__device__ __forceinline__ void attn_tile(
    int m0, const unsigned short* __restrict__ kb,
    const unsigned short* __restrict__ vb, int c, int g,
#ifdef HAVE_MFMA16
    const bf16x4* qf,
#else
    const bf16x8* qf,
#endif
    f32x4* acc, float* mrun, float* srun)
{
    float p[2][16];
#ifdef HAVE_MFMA16
    #pragma unroll
    for (int t = 0; t < 4; ++t) {
        int mm = m0 + c + t * 16;
        if (MASK) mm = min(mm, L - 1);
        bf16x4 kf = *(const bf16x4*)(kb + (size_t)mm * 16 + g * 4);   // shared
        f32x4 s0 = __builtin_amdgcn_mfma_f32_16x16x16bf16_1k(
            kf, qf[0], (f32x4){0.f,0.f,0.f,0.f}, 0, 0, 0);
        f32x4 s1 = __builtin_amdgcn_mfma_f32_16x16x16bf16_1k(
            kf, qf[1], (f32x4){0.f,0.f,0.f,0.f}, 0, 0, 0);
        #pragma unroll
        for (int r = 0; r < 4; ++r) {
            p[0][t * 4 + r] = s0[r];
            p[1][t * 4 + r] = s1[r];
        }
    }
#else
    #pragma unroll
    for (int t = 0; t < 4; ++t) {
        bf16x8 kf = (bf16x8){0,0,0,0,0,0,0,0};
        if (g < 2) {
            int mm = m0 + c + t * 16;
            if (MASK) mm = min(mm, L - 1);
            kf = *(const bf16x8*)(kb + (size_t)mm * 16 + g * 8);
        }
        f32x4 s0 = __builtin_amdgcn_mfma_f32_16x16x32_bf16(
            kf, qf[0], (f32x4){0.f,0.f,0.f,0.f}, 0, 0, 0);
        f32x4 s1 = __builtin_amdgcn_mfma_f32_16x16x32_bf16(
            kf, qf[1], (f32x4){0.f,0.f,0.f,0.f}, 0, 0, 0);
        #pragma unroll
        for (int r = 0; r < 4; ++r) {
            p[0][t * 4 + r] = s0[r];
            p[1][t * 4 + r] = s1[r];
        }
    }
#endif

    #pragma unroll
    for (int ch = 0; ch < 2; ++ch) {
        float tmax = -1e30f;
        #pragma unroll
        for (int t = 0; t < 4; ++t) {
            #pragma unroll
            for (int r = 0; r < 4; ++r) {
                float v = p[ch][t * 4 + r];
                if (MASK) {
                    int m = m0 + t * 16 + g * 4 + r;
                    if (m >= L) v = -1e30f;
                    p[ch][t * 4 + r] = v;
                }
                tmax = fmaxf(tmax, v);
            }
        }
        tmax = fmaxf(tmax, __shfl_xor(tmax, 16, 64));
        tmax = fmaxf(tmax, __shfl_xor(tmax, 32, 64));
        if (!__all(tmax <= mrun[ch])) {
            float mnew = fmaxf(mrun[ch], tmax);
            float corr = EXP2(mrun[ch] - mnew);
            srun[ch] *= corr;
            #pragma unroll
            for (int r = 0; r < 4; ++r) acc[ch][r] *= corr;
            mrun[ch] = mnew;
        }
        float ps0 = 0.f, ps1 = 0.f, ps2 = 0.f, ps3 = 0.f;
        #pragma unroll
        for (int t = 0; t < 4; ++t) {
            p[ch][t * 4 + 0] = EXP2(p[ch][t * 4 + 0] - mrun[ch]); ps0 += p[ch][t * 4 + 0];
            p[ch][t * 4 + 1] = EXP2(p[ch][t * 4 + 1] - mrun[ch]); ps1 += p[ch][t * 4 + 1];
            p[ch][t * 4 + 2] = EXP2(p[ch][t * 4 + 2] - mrun[ch]); ps2 += p[ch][t * 4 + 2];
            p[ch][t * 4 + 3] = EXP2(p[ch][t * 4 + 3] - mrun[ch]); ps3 += p[ch][t * 4 + 3];
        }
        srun[ch] += (ps0 + ps1) + (ps2 + ps3);
    }

#ifdef HAVE_MFMA16
    #pragma unroll
    for (int t = 0; t < 4; ++t) {
        bf16x4 vf = *(const bf16x4*)(vb + m0 + t * 16 + g * 4);           // shared
        bf16x4 pb0, pb1;
        #pragma unroll
        for (int j = 0; j < 4; ++j) {
            pb0[j] = (short)f2bf(p[0][t * 4 + j]);
            pb1[j] = (short)f2bf(p[1][t * 4 + j]);
        }
        acc[0] = __builtin_amdgcn_mfma_f32_16x16x16bf16_1k(vf, pb0, acc[0], 0, 0, 0);
        acc[1] = __builtin_amdgcn_mfma_f32_16x16x16bf16_1k(vf, pb1, acc[1], 0, 0, 0);
    }
#else
    int hi = g >> 1;
    #pragma unroll
    for (int H = 0; H < 2; ++H) {
        bf16x8 vf = *(const bf16x8*)(vb + m0 + H * 32 + g * 8);           // shared
        #pragma unroll
        for (int ch = 0; ch < 2; ++ch) {
            bf16x8 pb;
            #pragma unroll
            for (int j = 0; j < 8; ++j) {
                int srcLane = (((2 * g + (j >> 2)) & 3) << 4) | c;
                float v1 = __shfl(p[ch][(H * 2) * 4 + (j & 3)], srcLane, 64);
                float v2 = __shfl(p[ch][(H * 2 + 1) * 4 + (j & 3)], srcLane, 64);
                pb[j] = (short)f2bf(hi ? v2 : v1);
            }
            acc[ch] = __builtin_amdgcn_mfma_f32_16x16x32_bf16(vf, pb, acc[ch], 0, 0, 0);
        }
    }
#endif
}

// ---------------- MFMA flash attention: 2 query-chains per wave ---------------
template<int L, int LP>
__device__ __forceinline__ void attn_body(
    const unsigned short* __restrict__ Q, const unsigned short* __restrict__ Kt,
    const unsigned short* __restrict__ V, unsigned short* __restrict__ O,
    int lblk, int bh)
{
    constexpr int NFULL = L / 64;
    constexpr int TAIL  = L % 64;

    int tid  = threadIdx.x;
    int lane = tid & 63;
    int wv   = tid >> 6;
    int c    = lane & 15;
    int g    = lane >> 4;
    int b = bh >> 2, h = bh & 3;
    const unsigned short* qb = Q + (size_t)(b * 64 + h * 16) * L;
    const unsigned short* kb = Kt + (size_t)bh * L * 16;
    const unsigned short* vb = V + (size_t)(b * 64 + h * 16) * LP + (size_t)c * LP;
    unsigned short* ob = O + (size_t)(b * 64 + h * 16) * L;

    int lbase = lblk * 128 + wv * 16 + c;
    int l[2] = {lbase, lbase + 64};
    bool lval[2];
    int lc[2];
    #pragma unroll
    for (int ch = 0; ch < 2; ++ch) {
        lval[ch] = (l[ch] < L);
        lc[ch] = lval[ch] ? l[ch] : (L - 1);
    }

    f32x4 acc[2];
    float mrun[2], srun[2];
    #pragma unroll
    for (int ch = 0; ch < 2; ++ch) {
        acc[ch] = (f32x4){0.f, 0.f, 0.f, 0.f};
        mrun[ch] = -1e30f; srun[ch] = 0.f;
    }

#ifdef HAVE_MFMA16
    bf16x4 qf[2];
    #pragma unroll
    for (int ch = 0; ch < 2; ++ch)
        #pragma unroll
        for (int j = 0; j < 4; ++j) qf[ch][j] = (short)qb[(g * 4 + j) * L + lc[ch]];
#else
    bf16x8 qf[2];
    #pragma unroll
    for (int ch = 0; ch < 2; ++ch) {
        qf[ch] = (bf16x8){0,0,0,0,0,0,0,0};
        if (g < 2) {
            #pragma unroll
            for (int j = 0; j < 8; ++j) qf[ch][j] = (short)qb[(g * 8 + j) * L + lc[ch]];
        }
    }
#endif

    for (int mt = 0; mt < NFULL; ++mt)
        attn_tile<L, LP, false>(mt * 64, kb, vb, c, g, qf, acc, mrun, srun);
    if (TAIL > 0)
        attn_tile<L, LP, true>(NFULL * 64, kb, vb, c, g, qf, acc, mrun, srun);

    #pragma unroll
    for (int ch = 0; ch < 2; ++ch) {
        float stot = srun[ch];
        stot += __shfl_xor(stot, 16, 64);
        stot += __shfl_xor(stot, 32, 64);
        float inv = 1.f / stot;
        if (lval[ch]) {
            #pragma unroll
            for (int r = 0; r < 4; ++r)
                ob[(size_t)(g * 4 + r) * L + l[ch]] = f2bf(acc[ch][r] * inv);
        }
    }
}

__global__ __launch_bounds__(256) void attn_c_k(
    const unsigned short* __restrict__ Qa, const unsigned short* __restrict__ Ka,
    const unsigned short* __restrict__ Va, unsigned short* __restrict__ Oa)
{
    int bid = blockIdx.x;
    if (bid < 640) {                               // chunk0: 5 lblk x 128 bh
        attn_body<625, 632>(Qa, Ka, Va, Oa, bid % 5, bid / 5);
    } else if (bid < 1664) {                       // chunk1: 2 lblk x 512 bh
        int k = bid - 640;
        attn_body<256, 256>(Qa + 1280000, Ka + 1280000, Va + 1294336,
                            Oa + 1280000, k % 2, k / 2);
    } else {                                       // chunk2: 2 lblk x 1152 bh
        int k = bid - 1664;
        attn_body<144, 144>(Qa + 3377152, Ka + 3377152, Va + 3391488,
                            Oa + 3377152, k % 2, k / 2);
    }
}

// ---------------- proj + residual body (templated), bf16 O + bf16 U -----------
template<int L, int NPIX>
__device__ __forceinline__ void proj_body(
    unsigned short (*lds)[72],
    const unsigned short* __restrict__ O, const unsigned short* __restrict__ U,
    const float* __restrict__ pw, float* __restrict__ A, int bid)
{
    int tid  = threadIdx.x;
    int lane = tid & 63;
    int wv   = tid >> 6;
    int c    = lane & 15;
    int g8   = (lane >> 4) * 8;
    int q0   = bid * 64;

    int sp = tid >> 2;
    int sk = (tid & 3) * 8;
    int qc = min(q0 + sp, NPIX - 1);
    int b  = qc / L, p = qc % L;
    const unsigned short* ob = O + (size_t)b * 64 * L + p;

    bf16x8 b0, b1;
    #pragma unroll
    for (int j = 0; j < 8; ++j) {
        b0[j] = (short)ob[(size_t)(sk + j) * L];
        b1[j] = (short)ob[(size_t)(32 + sk + j) * L];
    }
    __syncthreads();
    *(bf16x8*)(&lds[sp][sk])      = b0;
    *(bf16x8*)(&lds[sp][32 + sk]) = b1;
    __syncthreads();

    f32x4 acc[4];
    #pragma unroll
    for (int f = 0; f < 4; ++f) acc[f] = (f32x4){0.f, 0.f, 0.f, 0.f};

    const float* arow = pw + (size_t)(wv * 16 + c) * 64;
    #pragma unroll
    for (int h = 0; h < 2; ++h) {
        bf16x8 a;
        const float* ap = arow + h * 32 + g8;
        #pragma unroll
        for (int j = 0; j < 8; ++j) a[j] = (short)f2bf(ap[j]);
        #pragma unroll
        for (int f = 0; f < 4; ++f) {
            bf16x8 bfr = *(const bf16x8*)(&lds[f * 16 + c][h * 32 + g8]);
            acc[f] = __builtin_amdgcn_mfma_f32_16x16x32_bf16(a, bfr, acc[f], 0, 0, 0);
        }
    }

    #pragma unroll
    for (int f = 0; f < 4; ++f) {
        int qq = q0 + f * 16 + c;
        if (qq < NPIX) {
            int bo = qq / L, po = qq % L;
            #pragma unroll
            for (int r = 0; r < 4; ++r) {
                int co = wv * 16 + (lane >> 4) * 4 + r;
                size_t oi = (size_t)(bo * 64 + co) * L + po;
                A[oi] = acc[f][r] + bf2f(U[oi]);
            }
        }
    }
}

__global__ __launch_bounds__(256) void proj_c_k(
    const unsigned short* __restrict__ Oa, const unsigned short* __restrict__ Uall,
    const float* __restrict__ pw, float* __restrict__ Aa)
{
    __shared__ unsigned short lds[64][72];
    int bid = blockIdx.x;
    if (bid < 313)
        proj_body<625, 20000>(lds, Oa, Uall, pw, Aa, bid);
    else if (bid < 825)
        proj_body<256, 32768>(lds, Oa + 1280000, Uall + 1280000, pw, Aa + 1280000, bid - 313);
    else
        proj_body<144, 41472>(lds, Oa + 3377152, Uall + 3377152, pw, Aa + 3377152, bid - 825);
}

// ---------------- padU body (templated), bf16 U input -------------------------
template<int KH, int PW, int L>
__device__ __forceinline__ void padU_body(
    const unsigned short* __restrict__ U, unsigned short* __restrict__ Up, int idx)
{
    int pp = idx % (PW * PW);
    int b  = idx / (PW * PW);
    int xx = pp % PW, yy = pp / PW;
    bool inter = (xx >= 1 && xx <= KH && yy >= 1 && yy <= KH);
    const unsigned short* up = U + (size_t)b * 64 * L + (yy - 1) * KH + (xx - 1);
    unsigned short vals[64];
    #pragma unroll
    for (int j = 0; j < 64; ++j) vals[j] = inter ? up[(size_t)j * L] : 0;
    unsigned short* op = Up + (size_t)idx * 64;
    #pragma unroll
    for (int v = 0; v < 8; ++v) {
        bf16x8 pack;
        #pragma unroll
        for (int j = 0; j < 8; ++j) pack[j] = (short)vals[v * 8 + j];
        *(bf16x8*)(op + v * 8) = pack;
    }
}

__global__ __launch_bounds__(256) void padU_c_k(
    const unsigned short* __restrict__ Uall, unsigned short* __restrict__ Upa)
{
    int idx = blockIdx.x * 256 + threadIdx.x;
    if (idx < 23328)        padU_body<25, 27, 625>(Uall,            Upa,            idx);
    else if (idx < 64800)   padU_body<16, 18, 256>(Uall + 1280000,  Upa + 1492992,  idx - 23328);
    else if (idx < 121248)  padU_body<12, 14, 144>(Uall + 3377152,  Upa + 4147200,  idx - 64800);
}

// ---------------- posconv body (templated), LDS dbuf --------------------------
template<int L, int PW, int KH, int NPIX>
__device__ __forceinline__ void posconv_body(
    unsigned short (*lds)[64][72],
    const unsigned short* __restrict__ Up, const unsigned short* __restrict__ Wb,
    const float* __restrict__ g, const float* __restrict__ bb,
    float* __restrict__ A, int bid)
{
    int tid  = threadIdx.x;
    int lane = tid & 63;
    int wv   = tid >> 6;
    int c    = lane & 15;
    int g8   = (lane >> 4) * 8;
    int p0   = bid * 64;

    int sp = tid >> 2;
    int sk = (tid & 3) * 8;
    int qq0 = p0 + sp;
    int po = 0;
    if (qq0 < NPIX) {
        int b = qq0 / L, p = qq0 % L;
        po = b * PW * PW + (p / KH) * PW + (p % KH);
    }

    const unsigned short* arow = Wb + (size_t)(wv * 16 + c) * KPOS_;

    f32x4 acc[4];
    #pragma unroll
    for (int f = 0; f < 4; ++f) acc[f] = (f32x4){0.f, 0.f, 0.f, 0.f};

    const int NT = KPOS_ / 64;                // 9

    bf16x8 b0, b1, a0, a1;
    {
        const unsigned short* bp = Up + ((size_t)po << 6);
        b0 = *(const bf16x8*)(bp + sk);
        b1 = *(const bf16x8*)(bp + 32 + sk);
        *(bf16x8*)(&lds[0][sp][sk])      = b0;
        *(bf16x8*)(&lds[0][sp][32 + sk]) = b1;
    }
    {
        const unsigned short* bp = Up + ((size_t)(po + 1) << 6);  // tap 1
        b0 = *(const bf16x8*)(bp + sk);
        b1 = *(const bf16x8*)(bp + 32 + sk);
    }
    a0 = *(const bf16x8*)(arow + g8);
    a1 = *(const bf16x8*)(arow + 32 + g8);

    for (int t = 0; t < NT; ++t) {
        __syncthreads();
        bf16x8 bf0[4], bf1[4];
        #pragma unroll
        for (int f = 0; f < 4; ++f) {
            bf0[f] = *(const bf16x8*)(&lds[t & 1][f * 16 + c][g8]);
            bf1[f] = *(const bf16x8*)(&lds[t & 1][f * 16 + c][32 + g8]);
        }
        if (t + 1 < NT) {
            *(bf16x8*)(&lds[(t + 1) & 1][sp][sk])      = b0;
            *(bf16x8*)(&lds[(t + 1) & 1][sp][32 + sk]) = b1;
            if (t + 2 < NT) {
                int tap = t + 2;
                int toff = (tap / 3) * PW + (tap % 3);
                const unsigned short* bp = Up + ((size_t)(po + toff) << 6);
                b0 = *(const bf16x8*)(bp + sk);
                b1 = *(const bf16x8*)(bp + 32 + sk);
            }
        }
        bf16x8 a0n, a1n;
        if (t + 1 < NT) {
            a0n = *(const bf16x8*)(arow + (t + 1) * 64 + g8);
            a1n = *(const bf16x8*)(arow + (t + 1) * 64 + 32 + g8);
        }
        #pragma unroll
        for (int f = 0; f < 4; ++f) {
            acc[f] = __builtin_amdgcn_mfma_f32_16x16x32_bf16(a0, bf0[f], acc[f], 0, 0, 0);
            acc[f] = __builtin_amdgcn_mfma_f32_16x16x32_bf16(a1, bf1[f], acc[f], 0, 0, 0);
        }
        a0 = a0n; a1 = a1n;
    }

    #pragma unroll
    for (int f = 0; f < 4; ++f) {
        int q = p0 + f * 16 + c;
        if (q < NPIX) {
            int b = q / L, p = q % L;
            #pragma unroll
            for (int r = 0; r < 4; ++r) {
                int co = wv * 16 + (lane >> 4) * 4 + r;
                A[(size_t)(b * 64 + co) * L + p] += acc[f][r] * bn_scale(g[co]) + bb[co];
            }
        }
    }
}

__global__ __launch_bounds__(256) void posconv_c_k(
    const unsigned short* __restrict__ Upa, const unsigned short* __restrict__ Wb,
    const float* __restrict__ g, const float* __restrict__ bb,
    float* __restrict__ Aa)
{
    __shared__ unsigned short lds[2][64][72];
    int bid = blockIdx.x;
    if (bid < 313)
        posconv_body<625, 27, 25, 20000>(lds, Upa, Wb, g, bb, Aa, bid);
    else if (bid < 825)
        posconv_body<256, 18, 16, 32768>(lds, Upa + 1492992, Wb, g, bb, Aa + 1280000, bid - 313);
    else
        posconv_body<144, 14, 12, 41472>(lds, Upa + 4147200, Wb, g, bb, Aa + 3377152, bid - 825);
}

// ---------------- fold body: writes conv2's NHWC bf16 input directly ----------
template<int NW, int SH, int KH>
__device__ __forceinline__ void fold_body(
    const float* __restrict__ A, unsigned short* __restrict__ Xb, int idx, int cidx)
{
    int w  = idx % HW_;
    int h  = (idx / HW_) % HW_;
    int cb = (idx / PIX_) % CB_;
    int n  = idx / (PIX_ * CB_);
    int numh = h - KH + 1;
    int ilo = numh > 0 ? (numh + SH - 1) / SH : 0;
    int ihi = min(NW - 1, h / SH);
    int numw = w - KH + 1;
    int jlo = numw > 0 ? (numw + SH - 1) / SH : 0;
    int jhi = min(NW - 1, w / SH);
    float sum = 0.f;
    for (int i = ilo; i <= ihi; ++i) {
        int r = h - i * SH;
        for (int j = jlo; j <= jhi; ++j) {
            int c = w - j * SH;
            int f = ((((n * CB_ + cb) * KH + r) * KH + c) * NW + i) * NW + j;
            sum += A[f];
        }
    }
    float cnt = (float)((ihi - ilo + 1) * (jhi - jlo + 1));
    Xb[((size_t)n * PADPIX_ + (h + 1) * PADW_ + (w + 1)) * 192 + cidx * CB_ + cb]
        = f2bf(sum / cnt);
}

__global__ __launch_bounds__(256) void fold_c_k(
    const float* __restrict__ Aa, unsigned short* __restrict__ Xb)
{
    int idx = blockIdx.x * 256 + threadIdx.x;
    if (idx < 1280000)       fold_body<4, 25, 25>(Aa,            Xb, idx,            0);
    else if (idx < 2560000)  fold_body<8, 12, 16>(Aa + 1280000,  Xb, idx - 1280000,  1);
    else if (idx < 3840000)  fold_body<12, 8, 12>(Aa + 3377152,  Xb, idx - 2560000,  2);
}

// ---------------- prep: zero pad ring of NHWC buffer --------------------------
__global__ __launch_bounds__(256) void ring_zero_k(unsigned short* __restrict__ Xb)
{
    int idx = blockIdx.x * 256 + threadIdx.x;
    if (idx >= N_ * 404 * 192) return;
    int cc = idx % 192;
    int rp = (idx / 192) % 404;
    int n  = idx / (192 * 404);
    int yy, xx;
    if (rp < 102)      { yy = 0;            xx = rp; }
    else if (rp < 204) { yy = 101;          xx = rp - 102; }
    else if (rp < 304) { yy = rp - 204 + 1; xx = 0; }
    else               { yy = rp - 304 + 1; xx = 101; }
    Xb[((size_t)n * PADPIX_ + yy * PADW_ + xx) * 192 + cc] = 0;
}

// ---------------- 3x3 conv implicit GEMM, NHWC bf16, XCD swizzle + LDS dbuf ---
#define NB3_ (157*3*2)
template<bool RES, bool TOXB>
__global__ __launch_bounds__(256) void conv3x3_mfma_k(
    const unsigned short* __restrict__ Xp,
    const unsigned short* __restrict__ Wb,
    const float* __restrict__ g, const float* __restrict__ bb,
    const float* __restrict__ res, float* __restrict__ out,
    unsigned short* __restrict__ xout)
{
    __shared__ unsigned short lds[2][64][72];
    int tid  = threadIdx.x;
    int lane = tid & 63;
    int wv   = tid >> 6;
    int c    = lane & 15;
    int g8   = (lane >> 4) * 8;

    const int q = NB3_ / 8, r = NB3_ % 8;
    int gid  = blockIdx.x;
    int xcd  = gid % 8, slot = gid / 8;
    int wgid = (xcd < r) ? xcd * (q + 1) + slot
                         : r * (q + 1) + (xcd - r) * q + slot;
    int co0  = (wgid % 3) * 64;
    int rest = wgid / 3;
    int p0   = (rest % 157) * 64;
    int n    = rest / 157;

    const unsigned short* Xn = Xp + (size_t)n * PADPIX_ * 192;

    int sp = tid >> 2;
    int sk = (tid & 3) * 8;
    int pix = p0 + sp;
    int po = (pix < PIX_) ? (pix / HW_) * PADW_ + (pix % HW_) : 0;

    const unsigned short* arow = Wb + (size_t)(co0 + wv * 16 + c) * KTOT_;

    f32x4 acc[4];
    #pragma unroll
    for (int f = 0; f < 4; ++f) acc[f] = (f32x4){0.f, 0.f, 0.f, 0.f};

    const int NT = KTOT_ / 64;

    bf16x8 b0, b1, a0, a1;
    {
        const unsigned short* bp = Xn + (size_t)po * 192;
        b0 = *(const bf16x8*)(bp + sk);
        b1 = *(const bf16x8*)(bp + 32 + sk);
        *(bf16x8*)(&lds[0][sp][sk])      = b0;
        *(bf16x8*)(&lds[0][sp][32 + sk]) = b1;
    }
    {
        const unsigned short* bp = Xn + (size_t)po * 192 + 64;
        b0 = *(const bf16x8*)(bp + sk);
        b1 = *(const bf16x8*)(bp + 32 + sk);
    }
    a0 = *(const bf16x8*)(arow + g8);
    a1 = *(const bf16x8*)(arow + 32 + g8);

    for (int t = 0; t < NT; ++t) {
        __syncthreads();
        bf16x8 bf0[4], bf1[4];
        #pragma unroll
        for (int f = 0; f < 4; ++f) {
            bf0[f] = *(const bf16x8*)(&lds[t & 1][f * 16 + c][g8]);
            bf1[f] = *(const bf16x8*)(&lds[t & 1][f * 16 + c][32 + g8]);
        }
        if (t + 1 < NT) {
            *(bf16x8*)(&lds[(t + 1) & 1][sp][sk])      = b0;
            *(bf16x8*)(&lds[(t + 1) & 1][sp][32 + sk]) = b1;
            if (t + 2 < NT) {
                int k2 = (t + 2) * 64;
                int tap = k2 / 192;
                int ci0 = k2 - tap * 192;
                int toff = (tap / 3) * PADW_ + (tap % 3);
                const unsigned short* bp = Xn + (size_t)(po + toff) * 192 + ci0;
                b0 = *(const bf16x8*)(bp + sk);
                b1 = *(const bf16x8*)(bp + 32 + sk);
            }
        }
        bf16x8 a0n, a1n;
        if (t + 1 < NT) {
            a0n = *(const bf16x8*)(arow + (t + 1) * 64 + g8);
            a1n = *(const bf16x8*)(arow + (t + 1) * 64 + 32 + g8);
        }
        #pragma unroll
        for (int f = 0; f < 4; ++f) {
            acc[f] = __builtin_amdgcn_mfma_f32_16x16x32_bf16(a0, bf0[f], acc[f], 0, 0, 0);
            acc[f] = __builtin_amdgcn_mfma_f32_16x16x32_bf16(a1, bf1[f], acc[f], 0, 0, 0);
        }
        a0 = a0n; a1 = a1n;
    }

    #pragma unroll
    for (int f = 0; f < 4; ++f) {
        int p = p0 + f * 16 + c;
        if (p < PIX_) {
            if (TOXB) {
                int py = p / HW_, px = p % HW_;
                unsigned short* o = xout +
                    ((size_t)n * PADPIX_ + (py + 1) * PADW_ + (px + 1)) * 192 +
                    co0 + wv * 16 + (lane >> 4) * 4;
                ushort4 pk;
                #pragma unroll
                for (int r2 = 0; r2 < 4; ++r2) {
                    int co = co0 + wv * 16 + (lane >> 4) * 4 + r2;
                    float v = acc[f][r2] * bn_scale(g[co]) + bb[co];
                    if (RES) v += res[(size_t)(n * C_ + co) * PIX_ + p];
                    ((unsigned short*)&pk)[r2] = f2bf(v);
                }
                *(ushort4*)o = pk;
            } else {
                #pragma unroll
                for (int r2 = 0; r2 < 4; ++r2) {
                    int co = co0 + wv * 16 + (lane >> 4) * 4 + r2;
                    float v = acc[f][r2] * bn_scale(g[co]) + bb[co];
                    if (RES) v += res[(size_t)(n * C_ + co) * PIX_ + p];
                    out[(size_t)(n * C_ + co) * PIX_ + p] = v;
                }
            }
        }
    }
}

extern "C" void kernel_launch(void* const* d_in, const int* in_sizes, int n_in,
                              void* d_out, int out_size, void* d_ws, size_t ws_size,
                              hipStream_t stream) {
    const float* x       = (const float*)d_in[0];
    const float* conv1_w = (const float*)d_in[1];
    const float* bn1_g   = (const float*)d_in[2];
    const float* bn1_b   = (const float*)d_in[3];
    const float* conv2_w = (const float*)d_in[4];
    const float* bn2_g   = (const float*)d_in[5];
    const float* bn2_b   = (const float*)d_in[6];
    const float* conv3_w = (const float*)d_in[7];
    const float* bn3_g   = (const float*)d_in[8];
    const float* bn3_b   = (const float*)d_in[9];
    const float* pos_w   = (const float*)d_in[10];
    const float* bnp_g   = (const float*)d_in[11];
    const float* bnp_b   = (const float*)d_in[12];
    const float* q_w     = (const float*)d_in[13];
    const float* k_w     = (const float*)d_in[14];
    const float* v_w     = (const float*)d_in[15];
    const float* proj_w  = (const float*)d_in[16];

    float* ws = (float*)d_ws;
    float* x1   = ws;                                        // 3,840,000
    unsigned short* Xc    = (unsigned short*)(ws + 7680000); // 3,840,000 sh
    unsigned short* Uall  = (unsigned short*)(ws + 9600000); // 6,031,360 sh (bf16)
    unsigned short* Oall  = (unsigned short*)(ws + 15640000);// 6,031,360 sh
    float* Aall = ws + 21680000;                             // 6,031,360
    unsigned short* Qall  = (unsigned short*)(ws + 27720000);// 6,031,360 sh
    unsigned short* Ktall = (unsigned short*)(ws + 30740000);
    unsigned short* Vall  = (unsigned short*)(ws + 33760000);// 6,045,696 sh
    unsigned short* Upall = (unsigned short*)(ws + 36790000);// 7,759,872 sh
    unsigned short* pwb   = (unsigned short*)(ws + 40670000);
    unsigned short* w2b   = (unsigned short*)(ws + 40690000);
    unsigned short* w3b   = (unsigned short*)(ws + 40856000);
    unsigned short* Xb    = (unsigned short*)(ws + 41022000);// 3,995,136 sh
    unsigned short* Xb2   = (unsigned short*)(ws + 43020000);

    x_nhwc_k<<<(N_ * 4 * PIX_ + 255) / 256, 256, 0, stream>>>(x, Xc);
    conv1x1_mfma_k<<<dim3(157, 3, 2), 256, 0, stream>>>(Xc, conv1_w, bn1_g, bn1_b, x1);
    wcvt_all_k<<<(700416 + 255) / 256, 256, 0, stream>>>(pos_w, conv2_w, conv3_w, pwb, w2b, w3b);

    gather_c_k<<<(6031360 + 255) / 256, 256, 0, stream>>>(x1, Uall);
    qkv_c_k<<<1473, 256, 0, stream>>>(Uall, q_w, k_w, v_w, Qall, Ktall, Vall);
    attn_c_k<<<2688 + 1280, 256, 0, stream>>>(Qall, Ktall, Vall, Oall);
    proj_c_k<<<1473, 256, 0, stream>>>(Oall, Uall, proj_w, Aall);
    padU_c_k<<<(121248 + 255) / 256, 256, 0, stream>>>(Uall, Upall);
    posconv_c_k<<<1473, 256, 0, stream>>>(Upall, pwb, bnp_g, bnp_b, Aall);

    ring_zero_k<<<(N_ * 404 * 192 + 255) / 256, 256, 0, stream>>>(Xb);
    fold_c_k<<<(3840000 + 255) / 256, 256, 0, stream>>>(Aall, Xb);

    ring_zero_k<<<(N_ * 404 * 192 + 255) / 256, 256, 0, stream>>>(Xb2);
    conv3x3_mfma_k<true, true><<<NB3_, 256, 0, stream>>>(
        Xb, w2b, bn2_g, bn2_b, x1, nullptr, Xb2);
    conv3x3_mfma_k<false, false><<<NB3_, 256, 0, stream>>>(
        Xb2, w3b, bn3_g, bn3_b, nullptr, (float*)d_out, nullptr);
}

// Round 24
// 255.255 us; speedup vs baseline: 1.1559x; 1.0433x over previous
//
#include <hip/hip_runtime.h>
#include <hip/hip_bf16.h>

#define N_ 2
#define C_ 192
#define CB_ 64
#define HW_ 100
#define PIX_ (HW_*HW_)
#define PADW_ 102
#define PADPIX_ (PADW_*PADW_)
#define KTOT_ 1728
#define KPOS_ 576
#define QSCALE_ 0.3606737602222409f   // 0.25 * log2(e)

typedef __attribute__((ext_vector_type(8))) short bf16x8;
typedef __attribute__((ext_vector_type(4))) short bf16x4;
typedef __attribute__((ext_vector_type(4))) float f32x4;

#if defined(__has_builtin)
#if __has_builtin(__builtin_amdgcn_mfma_f32_16x16x16bf16_1k)
#define HAVE_MFMA16 1
#endif
#if __has_builtin(__builtin_amdgcn_exp2f)
#define EXP2(x) __builtin_amdgcn_exp2f(x)
#endif
#endif
#ifndef EXP2
#define EXP2(x) exp2f(x)
#endif

static __device__ __forceinline__ float bn_scale(float g) {
    return g * rsqrtf(1.0f + 1e-5f);
}

static __device__ __forceinline__ unsigned short f2bf(float v) {
    __hip_bfloat16 h = __float2bfloat16(v);
    return *(unsigned short*)&h;
}

static __device__ __forceinline__ float bf2f(unsigned short u) {
    unsigned int v = ((unsigned int)u) << 16;
    return __uint_as_float(v);
}

// ---------------- prep: fp32 NCHW x -> bf16 channel-last [n][PIX][192] --------
__global__ __launch_bounds__(256) void x_nhwc_k(
    const float* __restrict__ in, unsigned short* __restrict__ out)
{
    int idx = blockIdx.x * 256 + threadIdx.x;
    if (idx >= N_ * 4 * PIX_) return;
    int p     = idx % PIX_;
    int chunk = (idx / PIX_) & 3;
    int n     = idx / (PIX_ * 4);
    int c0 = chunk * 48;
    const float* ip = in + ((size_t)n * C_ + c0) * PIX_ + p;
    unsigned short vals[48];
    #pragma unroll
    for (int j = 0; j < 48; ++j) vals[j] = f2bf(ip[(size_t)j * PIX_]);
    unsigned short* op = out + ((size_t)n * PIX_ + p) * 192 + c0;
    #pragma unroll
    for (int v = 0; v < 6; ++v) {
        bf16x8 pack;
        #pragma unroll
        for (int j = 0; j < 8; ++j) pack[j] = (short)vals[v * 8 + j];
        *(bf16x8*)(op + v * 8) = pack;
    }
}

// ---------------- conv1x1 + BN as GEMM, bf16 MFMA, NHWC input, bf16 out -------
__global__ __launch_bounds__(256) void conv1x1_mfma_k(
    const unsigned short* __restrict__ Xc,
    const float* __restrict__ w,
    const float* __restrict__ g, const float* __restrict__ bb,
    unsigned short* __restrict__ out)
{
    __shared__ unsigned short lds[64][72];
    int tid  = threadIdx.x;
    int lane = tid & 63;
    int wv   = tid >> 6;
    int c    = lane & 15;
    int g8   = (lane >> 4) * 8;
    int p0   = blockIdx.x * 64;
    int co0  = blockIdx.y * 64;
    int n    = blockIdx.z;

    int sp = tid >> 2;
    int sk = (tid & 3) * 8;
    int pc = min(p0 + sp, PIX_ - 1);
    const unsigned short* bp = Xc + ((size_t)n * PIX_ + pc) * 192;

    const float* arow = w + (size_t)(co0 + wv * 16 + c) * C_;

    f32x4 acc[4];
    #pragma unroll
    for (int f = 0; f < 4; ++f) acc[f] = (f32x4){0.f, 0.f, 0.f, 0.f};

    bf16x8 b0 = *(const bf16x8*)(bp + sk);
    bf16x8 b1 = *(const bf16x8*)(bp + 32 + sk);

    for (int k0 = 0; k0 < C_; k0 += 64) {
        __syncthreads();
        *(bf16x8*)(&lds[sp][sk])      = b0;
        *(bf16x8*)(&lds[sp][32 + sk]) = b1;
        __syncthreads();
        if (k0 + 64 < C_) {
            b0 = *(const bf16x8*)(bp + k0 + 64 + sk);
            b1 = *(const bf16x8*)(bp + k0 + 96 + sk);
        }
        #pragma unroll
        for (int h = 0; h < 2; ++h) {
            bf16x8 a;
            const float* ap = arow + k0 + h * 32 + g8;
            #pragma unroll
            for (int j = 0; j < 8; ++j) a[j] = (short)f2bf(ap[j]);
            #pragma unroll
            for (int f = 0; f < 4; ++f) {
                bf16x8 b = *(const bf16x8*)(&lds[f * 16 + c][h * 32 + g8]);
                acc[f] = __builtin_amdgcn_mfma_f32_16x16x32_bf16(a, b, acc[f], 0, 0, 0);
            }
        }
    }

    #pragma unroll
    for (int f = 0; f < 4; ++f) {
        int p = p0 + f * 16 + c;
        if (p < PIX_) {
            #pragma unroll
            for (int r = 0; r < 4; ++r) {
                int co = co0 + wv * 16 + (lane >> 4) * 4 + r;
                out[(size_t)(n * C_ + co) * PIX_ + p] =
                    f2bf(acc[f][r] * bn_scale(g[co]) + bb[co]);
            }
        }
    }
}

// ---------------- combined weight converts (pos + conv2 + conv3) -------------
__global__ __launch_bounds__(256) void wcvt_all_k(
    const float* __restrict__ pw, const float* __restrict__ w2,
    const float* __restrict__ w3,
    unsigned short* __restrict__ pwb, unsigned short* __restrict__ w2b,
    unsigned short* __restrict__ w3b)
{
    int idx = blockIdx.x * 256 + threadIdx.x;
    const int S0 = CB_ * KPOS_;          // 36864
    const int S1 = S0 + C_ * KTOT_;      // 368640
    const int S2 = S1 + C_ * KTOT_;      // 700416
    if (idx < S0) {
        int t = idx % 9, ci = (idx / 9) % CB_, co = idx / (9 * CB_);
        pwb[(size_t)co * KPOS_ + t * CB_ + ci] = f2bf(pw[idx]);
    } else if (idx < S1) {
        int k = idx - S0;
        int t = k % 9, ci = (k / 9) % C_, co = k / (9 * C_);
        w2b[(size_t)co * KTOT_ + t * C_ + ci] = f2bf(w2[k]);
    } else if (idx < S2) {
        int k = idx - S1;
        int t = k % 9, ci = (k / 9) % C_, co = k / (9 * C_);
        w3b[(size_t)co * KTOT_ + t * C_ + ci] = f2bf(w3[k]);
    }
}

// ---------------- combined gather (all 3 chunks), bf16 in/out -----------------
template<int NW, int SH, int KH>
__device__ __forceinline__ void gather_body(
    const unsigned short* __restrict__ x1, unsigned short* __restrict__ U,
    int f, int cidx)
{
    int t = f;
    int j = t % NW; t /= NW;
    int i = t % NW; t /= NW;
    int c = t % KH; t /= KH;
    int r = t % KH; t /= KH;
    int cb = t % CB_;
    int n  = t / CB_;
    int hh = i * SH + r;
    int ww = j * SH + c;
    U[f] = x1[((n * C_ + cidx * CB_ + cb) * HW_ + hh) * HW_ + ww];
}

__global__ __launch_bounds__(256) void gather_c_k(
    const unsigned short* __restrict__ x1, unsigned short* __restrict__ Uall)
{
    int gid = blockIdx.x * 256 + threadIdx.x;
    if (gid < 1280000)       gather_body<4, 25, 25>(x1, Uall,            gid,            0);
    else if (gid < 3377152)  gather_body<8, 12, 16>(x1, Uall + 1280000,  gid - 1280000,  1);
    else if (gid < 6031360)  gather_body<12, 8, 12>(x1, Uall + 3377152,  gid - 3377152,  2);
}

// ---------------- fused q/k/v GEMM body (templated L), bf16 U -----------------
template<int L, int LP, int NPIX>
__device__ __forceinline__ void qkv_body(
    unsigned short (*lds)[72],
    const unsigned short* __restrict__ U,
    const float* __restrict__ qw, const float* __restrict__ kw,
    const float* __restrict__ vw,
    unsigned short* __restrict__ Q, unsigned short* __restrict__ Kt,
    unsigned short* __restrict__ V, int bid)
{
    int tid  = threadIdx.x;
    int lane = tid & 63;
    int wv   = tid >> 6;
    int c    = lane & 15;
    int g8   = (lane >> 4) * 8;
    int q0   = bid * 64;

    int sp = tid >> 2;
    int sk = (tid & 3) * 8;
    int qc = min(q0 + sp, NPIX - 1);
    int b  = qc / L, p = qc % L;
    const unsigned short* ub = U + (size_t)b * 64 * L + p;

    bf16x8 b0, b1;
    #pragma unroll
    for (int j = 0; j < 8; ++j) {
        b0[j] = (short)ub[(size_t)(sk + j) * L];
        b1[j] = (short)ub[(size_t)(32 + sk + j) * L];
    }
    __syncthreads();
    *(bf16x8*)(&lds[sp][sk])      = b0;
    *(bf16x8*)(&lds[sp][32 + sk]) = b1;
    __syncthreads();

    f32x4 acc[3][4];
    #pragma unroll
    for (int s = 0; s < 3; ++s)
        #pragma unroll
        for (int f = 0; f < 4; ++f) acc[s][f] = (f32x4){0.f, 0.f, 0.f, 0.f};

    const float* wbase[3] = {qw, kw, vw};
    #pragma unroll
    for (int s = 0; s < 3; ++s) {
        const float* arow = wbase[s] + (size_t)(wv * 16 + c) * 64;
        #pragma unroll
        for (int h = 0; h < 2; ++h) {
            bf16x8 a;
            const float* ap = arow + h * 32 + g8;
            #pragma unroll
            for (int j = 0; j < 8; ++j) a[j] = (short)f2bf(ap[j]);
            #pragma unroll
            for (int f = 0; f < 4; ++f) {
                bf16x8 bfr = *(const bf16x8*)(&lds[f * 16 + c][h * 32 + g8]);
                acc[s][f] = __builtin_amdgcn_mfma_f32_16x16x32_bf16(a, bfr, acc[s][f], 0, 0, 0);
            }
        }
    }

    #pragma unroll
    for (int f = 0; f < 4; ++f) {
        int qq = q0 + f * 16 + c;
        if (qq < NPIX) {
            int bo = qq / L, po = qq % L;
            #pragma unroll
            for (int r = 0; r < 4; ++r) {
                int co = wv * 16 + (lane >> 4) * 4 + r;
                Q[(size_t)(bo * 64 + co) * L + po] = f2bf(acc[0][f][r] * QSCALE_);
                Kt[((size_t)(bo * 4 + wv) * L + po) * 16 + ((lane >> 4) * 4 + r)] = f2bf(acc[1][f][r]);
                V[(size_t)(bo * 64 + co) * LP + po] = f2bf(acc[2][f][r]);
            }
        }
    }
}

__global__ __launch_bounds__(256) void qkv_c_k(
    const unsigned short* __restrict__ Uall,
    const float* __restrict__ qw, const float* __restrict__ kw,
    const float* __restrict__ vw,
    unsigned short* __restrict__ Qa, unsigned short* __restrict__ Ka,
    unsigned short* __restrict__ Va)
{
    __shared__ unsigned short lds[64][72];
    int bid = blockIdx.x;
    if (bid < 313)
        qkv_body<625, 632, 20000>(lds, Uall, qw, kw, vw, Qa, Ka, Va, bid);
    else if (bid < 825)
        qkv_body<256, 256, 32768>(lds, Uall + 1280000, qw, kw, vw,
                                  Qa + 1280000, Ka + 1280000, Va + 1294336, bid - 313);
    else
        qkv_body<144, 144, 41472>(lds, Uall + 3377152, qw, kw, vw,
                                  Qa + 3377152, Ka + 3377152, Va + 3391488, bid - 825);
}

// ---------------- attention tile body (MASK only for the tail tile) -----------
template<int L, int LP, bool MASK>
__device__ __forceinline__ void attn_tile(
    int m0, const unsigned short* __restrict__ kb,
    const unsigned short* __restrict__ vb, int c, int g,
#ifdef HAVE_MFMA16
    const bf16x4* qf,
#else
    const bf16x8* qf,
#endif
    f32x4* acc, float* mrun, float* srun)
{
    float p[2][16];
#ifdef HAVE_MFMA16
    #pragma unroll
    for (int t = 0; t < 4; ++t) {
        int mm = m0 + c + t * 16;
        if (MASK) mm = min(mm, L - 1);
        bf16x4 kf = *(const bf16x4*)(kb + (size_t)mm * 16 + g * 4);   // shared
        f32x4 s0 = __builtin_amdgcn_mfma_f32_16x16x16bf16_1k(
            kf, qf[0], (f32x4){0.f,0.f,0.f,0.f}, 0, 0, 0);
        f32x4 s1 = __builtin_amdgcn_mfma_f32_16x16x16bf16_1k(
            kf, qf[1], (f32x4){0.f,0.f,0.f,0.f}, 0, 0, 0);
        #pragma unroll
        for (int r = 0; r < 4; ++r) {
            p[0][t * 4 + r] = s0[r];
            p[1][t * 4 + r] = s1[r];
        }
    }
#else
    #pragma unroll
    for (int t = 0; t < 4; ++t) {
        bf16x8 kf = (bf16x8){0,0,0,0,0,0,0,0};
        if (g < 2) {
            int mm = m0 + c + t * 16;
            if (MASK) mm = min(mm, L - 1);
            kf = *(const bf16x8*)(kb + (size_t)mm * 16 + g * 8);
        }
        f32x4 s0 = __builtin_amdgcn_mfma_f32_16x16x32_bf16(
            kf, qf[0], (f32x4){0.f,0.f,0.f,0.f}, 0, 0, 0);
        f32x4 s1 = __builtin_amdgcn_mfma_f32_16x16x32_bf16(
            kf, qf[1], (f32x4){0.f,0.f,0.f,0.f}, 0, 0, 0);
        #pragma unroll
        for (int r = 0; r < 4; ++r) {
            p[0][t * 4 + r] = s0[r];
            p[1][t * 4 + r] = s1[r];
        }
    }
#endif

    #pragma unroll
    for (int ch = 0; ch < 2; ++ch) {
        float tmax = -1e30f;
        #pragma unroll
        for (int t = 0; t < 4; ++t) {
            #pragma unroll
            for (int r = 0; r < 4; ++r) {
                float v = p[ch][t * 4 + r];
                if (MASK) {
                    int m = m0 + t * 16 + g * 4 + r;
                    if (m >= L) v = -1e30f;
                    p[ch][t * 4 + r] = v;
                }
                tmax = fmaxf(tmax, v);
            }
        }
        tmax = fmaxf(tmax, __shfl_xor(tmax, 16, 64));
        tmax = fmaxf(tmax, __shfl_xor(tmax, 32, 64));
        if (!__all(tmax <= mrun[ch])) {
            float mnew = fmaxf(mrun[ch], tmax);
            float corr = EXP2(mrun[ch] - mnew);
            srun[ch] *= corr;
            #pragma unroll
            for (int r = 0; r < 4; ++r) acc[ch][r] *= corr;
            mrun[ch] = mnew;
        }
        float ps0 = 0.f, ps1 = 0.f, ps2 = 0.f, ps3 = 0.f;
        #pragma unroll
        for (int t = 0; t < 4; ++t) {
            p[ch][t * 4 + 0] = EXP2(p[ch][t * 4 + 0] - mrun[ch]); ps0 += p[ch][t * 4 + 0];
            p[ch][t * 4 + 1] = EXP2(p[ch][t * 4 + 1] - mrun[ch]); ps1 += p[ch][t * 4 + 1];
            p[ch][t * 4 + 2] = EXP2(p[ch][t * 4 + 2] - mrun[ch]); ps2 += p[ch][t * 4 + 2];
            p[ch][t * 4 + 3] = EXP2(p[ch][t * 4 + 3] - mrun[ch]); ps3 += p[ch][t * 4 + 3];
        }
        srun[ch] += (ps0 + ps1) + (ps2 + ps3);
    }

#ifdef HAVE_MFMA16
    #pragma unroll
    for (int t = 0; t < 4; ++t) {
        bf16x4 vf = *(const bf16x4*)(vb + m0 + t * 16 + g * 4);           // shared
        bf16x4 pb0, pb1;
        #pragma unroll
        for (int j = 0; j < 4; ++j) {
            pb0[j] = (short)f2bf(p[0][t * 4 + j]);
            pb1[j] = (short)f2bf(p[1][t * 4 + j]);
        }
        acc[0] = __builtin_amdgcn_mfma_f32_16x16x16bf16_1k(vf, pb0, acc[0], 0, 0, 0);
        acc[1] = __builtin_amdgcn_mfma_f32_16x16x16bf16_1k(vf, pb1, acc[1], 0, 0, 0);
    }
#else
    int hi = g >> 1;
    #pragma unroll
    for (int H = 0; H < 2; ++H) {
        bf16x8 vf = *(const bf16x8*)(vb + m0 + H * 32 + g * 8);           // shared
        #pragma unroll
        for (int ch = 0; ch < 2; ++ch) {
            bf16x8 pb;
            #pragma unroll
            for (int j = 0; j < 8; ++j) {
                int srcLane = (((2 * g + (j >> 2)) & 3) << 4) | c;
                float v1 = __shfl(p[ch][(H * 2) * 4 + (j & 3)], srcLane, 64);
                float v2 = __shfl(p[ch][(H * 2 + 1) * 4 + (j & 3)], srcLane, 64);
                pb[j] = (short)f2bf(hi ? v2 : v1);
            }
            acc[ch] = __builtin_amdgcn_mfma_f32_16x16x32_bf16(vf, pb, acc[ch], 0, 0, 0);
        }
    }
#endif
}

// ---------------- MFMA flash attention: 2 query-chains per wave ---------------
template<int L, int LP>
__device__ __forceinline__ void attn_body(
    const unsigned short* __restrict__ Q, const unsigned short* __restrict__ Kt,
    const unsigned short* __restrict__ V, unsigned short* __restrict__ O,
    int lblk, int bh)
{
    constexpr int NFULL = L / 64;
    constexpr int TAIL  = L % 64;

    int tid  = threadIdx.x;
    int lane = tid & 63;
    int wv   = tid >> 6;
    int c    = lane & 15;
    int g    = lane >> 4;
    int b = bh >> 2, h = bh & 3;
    const unsigned short* qb = Q + (size_t)(b * 64 + h * 16) * L;
    const unsigned short* kb = Kt + (size_t)bh * L * 16;
    const unsigned short* vb = V + (size_t)(b * 64 + h * 16) * LP + (size_t)c * LP;
    unsigned short* ob = O + (size_t)(b * 64 + h * 16) * L;

    int lbase = lblk * 128 + wv * 16 + c;
    int l[2] = {lbase, lbase + 64};
    bool lval[2];
    int lc[2];
    #pragma unroll
    for (int ch = 0; ch < 2; ++ch) {
        lval[ch] = (l[ch] < L);
        lc[ch] = lval[ch] ? l[ch] : (L - 1);
    }

    f32x4 acc[2];
    float mrun[2], srun[2];
    #pragma unroll
    for (int ch = 0; ch < 2; ++ch) {
        acc[ch] = (f32x4){0.f, 0.f, 0.f, 0.f};
        mrun[ch] = -1e30f; srun[ch] = 0.f;
    }

#ifdef HAVE_MFMA16
    bf16x4 qf[2];
    #pragma unroll
    for (int ch = 0; ch < 2; ++ch)
        #pragma unroll
        for (int j = 0; j < 4; ++j) qf[ch][j] = (short)qb[(g * 4 + j) * L + lc[ch]];
#else
    bf16x8 qf[2];
    #pragma unroll
    for (int ch = 0; ch < 2; ++ch) {
        qf[ch] = (bf16x8){0,0,0,0,0,0,0,0};
        if (g < 2) {
            #pragma unroll
            for (int j = 0; j < 8; ++j) qf[ch][j] = (short)qb[(g * 8 + j) * L + lc[ch]];
        }
    }
#endif

    for (int mt = 0; mt < NFULL; ++mt)
        attn_tile<L, LP, false>(mt * 64, kb, vb, c, g, qf, acc, mrun, srun);
    if (TAIL > 0)
        attn_tile<L, LP, true>(NFULL * 64, kb, vb, c, g, qf, acc, mrun, srun);

    #pragma unroll
    for (int ch = 0; ch < 2; ++ch) {
        float stot = srun[ch];
        stot += __shfl_xor(stot, 16, 64);
        stot += __shfl_xor(stot, 32, 64);
        float inv = 1.f / stot;
        if (lval[ch]) {
            #pragma unroll
            for (int r = 0; r < 4; ++r)
                ob[(size_t)(g * 4 + r) * L + l[ch]] = f2bf(acc[ch][r] * inv);
        }
    }
}

__global__ __launch_bounds__(256) void attn_c_k(
    const unsigned short* __restrict__ Qa, const unsigned short* __restrict__ Ka,
    const unsigned short* __restrict__ Va, unsigned short* __restrict__ Oa)
{
    int bid = blockIdx.x;
    if (bid < 640) {                               // chunk0: 5 lblk x 128 bh
        attn_body<625, 632>(Qa, Ka, Va, Oa, bid % 5, bid / 5);
    } else if (bid < 1664) {                       // chunk1: 2 lblk x 512 bh
        int k = bid - 640;
        attn_body<256, 256>(Qa + 1280000, Ka + 1280000, Va + 1294336,
                            Oa + 1280000, k % 2, k / 2);
    } else {                                       // chunk2: 2 lblk x 1152 bh
        int k = bid - 1664;
        attn_body<144, 144>(Qa + 3377152, Ka + 3377152, Va + 3391488,
                            Oa + 3377152, k % 2, k / 2);
    }
}

// ---------------- proj + residual body, bf16 O + bf16 U -> bf16 A -------------
template<int L, int NPIX>
__device__ __forceinline__ void proj_body(
    unsigned short (*lds)[72],
    const unsigned short* __restrict__ O, const unsigned short* __restrict__ U,
    const float* __restrict__ pw, unsigned short* __restrict__ A, int bid)
{
    int tid  = threadIdx.x;
    int lane = tid & 63;
    int wv   = tid >> 6;
    int c    = lane & 15;
    int g8   = (lane >> 4) * 8;
    int q0   = bid * 64;

    int sp = tid >> 2;
    int sk = (tid & 3) * 8;
    int qc = min(q0 + sp, NPIX - 1);
    int b  = qc / L, p = qc % L;
    const unsigned short* ob = O + (size_t)b * 64 * L + p;

    bf16x8 b0, b1;
    #pragma unroll
    for (int j = 0; j < 8; ++j) {
        b0[j] = (short)ob[(size_t)(sk + j) * L];
        b1[j] = (short)ob[(size_t)(32 + sk + j) * L];
    }
    __syncthreads();
    *(bf16x8*)(&lds[sp][sk])      = b0;
    *(bf16x8*)(&lds[sp][32 + sk]) = b1;
    __syncthreads();

    f32x4 acc[4];
    #pragma unroll
    for (int f = 0; f < 4; ++f) acc[f] = (f32x4){0.f, 0.f, 0.f, 0.f};

    const float* arow = pw + (size_t)(wv * 16 + c) * 64;
    #pragma unroll
    for (int h = 0; h < 2; ++h) {
        bf16x8 a;
        const float* ap = arow + h * 32 + g8;
        #pragma unroll
        for (int j = 0; j < 8; ++j) a[j] = (short)f2bf(ap[j]);
        #pragma unroll
        for (int f = 0; f < 4; ++f) {
            bf16x8 bfr = *(const bf16x8*)(&lds[f * 16 + c][h * 32 + g8]);
            acc[f] = __builtin_amdgcn_mfma_f32_16x16x32_bf16(a, bfr, acc[f], 0, 0, 0);
        }
    }

    #pragma unroll
    for (int f = 0; f < 4; ++f) {
        int qq = q0 + f * 16 + c;
        if (qq < NPIX) {
            int bo = qq / L, po = qq % L;
            #pragma unroll
            for (int r = 0; r < 4; ++r) {
                int co = wv * 16 + (lane >> 4) * 4 + r;
                size_t oi = (size_t)(bo * 64 + co) * L + po;
                A[oi] = f2bf(acc[f][r] + bf2f(U[oi]));
            }
        }
    }
}

__global__ __launch_bounds__(256) void proj_c_k(
    const unsigned short* __restrict__ Oa, const unsigned short* __restrict__ Uall,
    const float* __restrict__ pw, unsigned short* __restrict__ Aa)
{
    __shared__ unsigned short lds[64][72];
    int bid = blockIdx.x;
    if (bid < 313)
        proj_body<625, 20000>(lds, Oa, Uall, pw, Aa, bid);
    else if (bid < 825)
        proj_body<256, 32768>(lds, Oa + 1280000, Uall + 1280000, pw, Aa + 1280000, bid - 313);
    else
        proj_body<144, 41472>(lds, Oa + 3377152, Uall + 3377152, pw, Aa + 3377152, bid - 825);
}

// ---------------- padU body (templated), bf16 U input -------------------------
template<int KH, int PW, int L>
__device__ __forceinline__ void padU_body(
    const unsigned short* __restrict__ U, unsigned short* __restrict__ Up, int idx)
{
    int pp = idx % (PW * PW);
    int b  = idx / (PW * PW);
    int xx = pp % PW, yy = pp / PW;
    bool inter = (xx >= 1 && xx <= KH && yy >= 1 && yy <= KH);
    const unsigned short* up = U + (size_t)b * 64 * L + (yy - 1) * KH + (xx - 1);
    unsigned short vals[64];
    #pragma unroll
    for (int j = 0; j < 64; ++j) vals[j] = inter ? up[(size_t)j * L] : 0;
    unsigned short* op = Up + (size_t)idx * 64;
    #pragma unroll
    for (int v = 0; v < 8; ++v) {
        bf16x8 pack;
        #pragma unroll
        for (int j = 0; j < 8; ++j) pack[j] = (short)vals[v * 8 + j];
        *(bf16x8*)(op + v * 8) = pack;
    }
}

__global__ __launch_bounds__(256) void padU_c_k(
    const unsigned short* __restrict__ Uall, unsigned short* __restrict__ Upa)
{
    int idx = blockIdx.x * 256 + threadIdx.x;
    if (idx < 23328)        padU_body<25, 27, 625>(Uall,            Upa,            idx);
    else if (idx < 64800)   padU_body<16, 18, 256>(Uall + 1280000,  Upa + 1492992,  idx - 23328);
    else if (idx < 121248)  padU_body<12, 14, 144>(Uall + 3377152,  Upa + 4147200,  idx - 64800);
}

// ---------------- posconv body (templated), LDS dbuf, bf16 A RMW --------------
template<int L, int PW, int KH, int NPIX>
__device__ __forceinline__ void posconv_body(
    unsigned short (*lds)[64][72],
    const unsigned short* __restrict__ Up, const unsigned short* __restrict__ Wb,
    const float* __restrict__ g, const float* __restrict__ bb,
    unsigned short* __restrict__ A, int bid)
{
    int tid  = threadIdx.x;
    int lane = tid & 63;
    int wv   = tid >> 6;
    int c    = lane & 15;
    int g8   = (lane >> 4) * 8;
    int p0   = bid * 64;

    int sp = tid >> 2;
    int sk = (tid & 3) * 8;
    int qq0 = p0 + sp;
    int po = 0;
    if (qq0 < NPIX) {
        int b = qq0 / L, p = qq0 % L;
        po = b * PW * PW + (p / KH) * PW + (p % KH);
    }

    const unsigned short* arow = Wb + (size_t)(wv * 16 + c) * KPOS_;

    f32x4 acc[4];
    #pragma unroll
    for (int f = 0; f < 4; ++f) acc[f] = (f32x4){0.f, 0.f, 0.f, 0.f};

    const int NT = KPOS_ / 64;                // 9

    bf16x8 b0, b1, a0, a1;
    {
        const unsigned short* bp = Up + ((size_t)po << 6);
        b0 = *(const bf16x8*)(bp + sk);
        b1 = *(const bf16x8*)(bp + 32 + sk);
        *(bf16x8*)(&lds[0][sp][sk])      = b0;
        *(bf16x8*)(&lds[0][sp][32 + sk]) = b1;
    }
    {
        const unsigned short* bp = Up + ((size_t)(po + 1) << 6);  // tap 1
        b0 = *(const bf16x8*)(bp + sk);
        b1 = *(const bf16x8*)(bp + 32 + sk);
    }
    a0 = *(const bf16x8*)(arow + g8);
    a1 = *(const bf16x8*)(arow + 32 + g8);

    for (int t = 0; t < NT; ++t) {
        __syncthreads();
        bf16x8 bf0[4], bf1[4];
        #pragma unroll
        for (int f = 0; f < 4; ++f) {
            bf0[f] = *(const bf16x8*)(&lds[t & 1][f * 16 + c][g8]);
            bf1[f] = *(const bf16x8*)(&lds[t & 1][f * 16 + c][32 + g8]);
        }
        if (t + 1 < NT) {
            *(bf16x8*)(&lds[(t + 1) & 1][sp][sk])      = b0;
            *(bf16x8*)(&lds[(t + 1) & 1][sp][32 + sk]) = b1;
            if (t + 2 < NT) {
                int tap = t + 2;
                int toff = (tap / 3) * PW + (tap % 3);
                const unsigned short* bp = Up + ((size_t)(po + toff) << 6);
                b0 = *(const bf16x8*)(bp + sk);
                b1 = *(const bf16x8*)(bp + 32 + sk);
            }
        }
        bf16x8 a0n, a1n;
        if (t + 1 < NT) {
            a0n = *(const bf16x8*)(arow + (t + 1) * 64 + g8);
            a1n = *(const bf16x8*)(arow + (t + 1) * 64 + 32 + g8);
        }
        #pragma unroll
        for (int f = 0; f < 4; ++f) {
            acc[f] = __builtin_amdgcn_mfma_f32_16x16x32_bf16(a0, bf0[f], acc[f], 0, 0, 0);
            acc[f] = __builtin_amdgcn_mfma_f32_16x16x32_bf16(a1, bf1[f], acc[f], 0, 0, 0);
        }
        a0 = a0n; a1 = a1n;
    }

    #pragma unroll
    for (int f = 0; f < 4; ++f) {
        int q = p0 + f * 16 + c;
        if (q < NPIX) {
            int b = q / L, p = q % L;
            #pragma unroll
            for (int r = 0; r < 4; ++r) {
                int co = wv * 16 + (lane >> 4) * 4 + r;
                size_t ai = (size_t)(b * 64 + co) * L + p;
                A[ai] = f2bf(bf2f(A[ai]) + acc[f][r] * bn_scale(g[co]) + bb[co]);
            }
        }
    }
}

__global__ __launch_bounds__(256) void posconv_c_k(
    const unsigned short* __restrict__ Upa, const unsigned short* __restrict__ Wb,
    const float* __restrict__ g, const float* __restrict__ bb,
    unsigned short* __restrict__ Aa)
{
    __shared__ unsigned short lds[2][64][72];
    int bid = blockIdx.x;
    if (bid < 313)
        posconv_body<625, 27, 25, 20000>(lds, Upa, Wb, g, bb, Aa, bid);
    else if (bid < 825)
        posconv_body<256, 18, 16, 32768>(lds, Upa + 1492992, Wb, g, bb, Aa + 1280000, bid - 313);
    else
        posconv_body<144, 14, 12, 41472>(lds, Upa + 4147200, Wb, g, bb, Aa + 3377152, bid - 825);
}

// ---------------- fold body: bf16 A -> conv2's NHWC bf16 input ----------------
template<int NW, int SH, int KH>
__device__ __forceinline__ void fold_body(
    const unsigned short* __restrict__ A, unsigned short* __restrict__ Xb,
    int idx, int cidx)
{
    int w  = idx % HW_;
    int h  = (idx / HW_) % HW_;
    int cb = (idx / PIX_) % CB_;
    int n  = idx / (PIX_ * CB_);
    int numh = h - KH + 1;
    int ilo = numh > 0 ? (numh + SH - 1) / SH : 0;
    int ihi = min(NW - 1, h / SH);
    int numw = w - KH + 1;
    int jlo = numw > 0 ? (numw + SH - 1) / SH : 0;
    int jhi = min(NW - 1, w / SH);
    float sum = 0.f;
    for (int i = ilo; i <= ihi; ++i) {
        int r = h - i * SH;
        for (int j = jlo; j <= jhi; ++j) {
            int c = w - j * SH;
            int f = ((((n * CB_ + cb) * KH + r) * KH + c) * NW + i) * NW + j;
            sum += bf2f(A[f]);
        }
    }
    float cnt = (float)((ihi - ilo + 1) * (jhi - jlo + 1));
    Xb[((size_t)n * PADPIX_ + (h + 1) * PADW_ + (w + 1)) * 192 + cidx * CB_ + cb]
        = f2bf(sum / cnt);
}

__global__ __launch_bounds__(256) void fold_c_k(
    const unsigned short* __restrict__ Aa, unsigned short* __restrict__ Xb)
{
    int idx = blockIdx.x * 256 + threadIdx.x;
    if (idx < 1280000)       fold_body<4, 25, 25>(Aa,            Xb, idx,            0);
    else if (idx < 2560000)  fold_body<8, 12, 16>(Aa + 1280000,  Xb, idx - 1280000,  1);
    else if (idx < 3840000)  fold_body<12, 8, 12>(Aa + 3377152,  Xb, idx - 2560000,  2);
}

// ---------------- prep: zero pad ring of NHWC buffer --------------------------
__global__ __launch_bounds__(256) void ring_zero_k(unsigned short* __restrict__ Xb)
{
    int idx = blockIdx.x * 256 + threadIdx.x;
    if (idx >= N_ * 404 * 192) return;
    int cc = idx % 192;
    int rp = (idx / 192) % 404;
    int n  = idx / (192 * 404);
    int yy, xx;
    if (rp < 102)      { yy = 0;            xx = rp; }
    else if (rp < 204) { yy = 101;          xx = rp - 102; }
    else if (rp < 304) { yy = rp - 204 + 1; xx = 0; }
    else               { yy = rp - 304 + 1; xx = 101; }
    Xb[((size_t)n * PADPIX_ + yy * PADW_ + xx) * 192 + cc] = 0;
}

// ---------------- 3x3 conv implicit GEMM, NHWC bf16, XCD swizzle + LDS dbuf ---
// RES reads bf16 residual; TOXB writes NHWC bf16 (conv3's input).
#define NB3_ (157*3*2)
template<bool RES, bool TOXB>
__global__ __launch_bounds__(256) void conv3x3_mfma_k(
    const unsigned short* __restrict__ Xp,
    const unsigned short* __restrict__ Wb,
    const float* __restrict__ g, const float* __restrict__ bb,
    const unsigned short* __restrict__ res, float* __restrict__ out,
    unsigned short* __restrict__ xout)
{
    __shared__ unsigned short lds[2][64][72];
    int tid  = threadIdx.x;
    int lane = tid & 63;
    int wv   = tid >> 6;
    int c    = lane & 15;
    int g8   = (lane >> 4) * 8;

    const int q = NB3_ / 8, r = NB3_ % 8;
    int gid  = blockIdx.x;
    int xcd  = gid % 8, slot = gid / 8;
    int wgid = (xcd < r) ? xcd * (q + 1) + slot
                         : r * (q + 1) + (xcd - r) * q + slot;
    int co0  = (wgid % 3) * 64;
    int rest = wgid / 3;
    int p0   = (rest % 157) * 64;
    int n    = rest / 157;

    const unsigned short* Xn = Xp + (size_t)n * PADPIX_ * 192;

    int sp = tid >> 2;
    int sk = (tid & 3) * 8;
    int pix = p0 + sp;
    int po = (pix < PIX_) ? (pix / HW_) * PADW_ + (pix % HW_) : 0;

    const unsigned short* arow = Wb + (size_t)(co0 + wv * 16 + c) * KTOT_;

    f32x4 acc[4];
    #pragma unroll
    for (int f = 0; f < 4; ++f) acc[f] = (f32x4){0.f, 0.f, 0.f, 0.f};

    const int NT = KTOT_ / 64;

    bf16x8 b0, b1, a0, a1;
    {
        const unsigned short* bp = Xn + (size_t)po * 192;
        b0 = *(const bf16x8*)(bp + sk);
        b1 = *(const bf16x8*)(bp + 32 + sk);
        *(bf16x8*)(&lds[0][sp][sk])      = b0;
        *(bf16x8*)(&lds[0][sp][32 + sk]) = b1;
    }
    {
        const unsigned short* bp = Xn + (size_t)po * 192 + 64;
        b0 = *(const bf16x8*)(bp + sk);
        b1 = *(const bf16x8*)(bp + 32 + sk);
    }
    a0 = *(const bf16x8*)(arow + g8);
    a1 = *(const bf16x8*)(arow + 32 + g8);

    for (int t = 0; t < NT; ++t) {
        __syncthreads();
        bf16x8 bf0[4], bf1[4];
        #pragma unroll
        for (int f = 0; f < 4; ++f) {
            bf0[f] = *(const bf16x8*)(&lds[t & 1][f * 16 + c][g8]);
            bf1[f] = *(const bf16x8*)(&lds[t & 1][f * 16 + c][32 + g8]);
        }
        if (t + 1 < NT) {
            *(bf16x8*)(&lds[(t + 1) & 1][sp][sk])      = b0;
            *(bf16x8*)(&lds[(t + 1) & 1][sp][32 + sk]) = b1;
            if (t + 2 < NT) {
                int k2 = (t + 2) * 64;
                int tap = k2 / 192;
                int ci0 = k2 - tap * 192;
                int toff = (tap / 3) * PADW_ + (tap % 3);
                const unsigned short* bp = Xn + (size_t)(po + toff) * 192 + ci0;
                b0 = *(const bf16x8*)(bp + sk);
                b1 = *(const bf16x8*)(bp + 32 + sk);
            }
        }
        bf16x8 a0n, a1n;
        if (t + 1 < NT) {
            a0n = *(const bf16x8*)(arow + (t + 1) * 64 + g8);
            a1n = *(const bf16x8*)(arow + (t + 1) * 64 + 32 + g8);
        }
        #pragma unroll
        for (int f = 0; f < 4; ++f) {
            acc[f] = __builtin_amdgcn_mfma_f32_16x16x32_bf16(a0, bf0[f], acc[f], 0, 0, 0);
            acc[f] = __builtin_amdgcn_mfma_f32_16x16x32_bf16(a1, bf1[f], acc[f], 0, 0, 0);
        }
        a0 = a0n; a1 = a1n;
    }

    #pragma unroll
    for (int f = 0; f < 4; ++f) {
        int p = p0 + f * 16 + c;
        if (p < PIX_) {
            if (TOXB) {
                int py = p / HW_, px = p % HW_;
                unsigned short* o = xout +
                    ((size_t)n * PADPIX_ + (py + 1) * PADW_ + (px + 1)) * 192 +
                    co0 + wv * 16 + (lane >> 4) * 4;
                ushort4 pk;
                #pragma unroll
                for (int r2 = 0; r2 < 4; ++r2) {
                    int co = co0 + wv * 16 + (lane >> 4) * 4 + r2;
                    float v = acc[f][r2] * bn_scale(g[co]) + bb[co];
                    if (RES) v += bf2f(res[(size_t)(n * C_ + co) * PIX_ + p]);
                    ((unsigned short*)&pk)[r2] = f2bf(v);
                }
                *(ushort4*)o = pk;
            } else {
                #pragma unroll
                for (int r2 = 0; r2 < 4; ++r2) {
                    int co = co0 + wv * 16 + (lane >> 4) * 4 + r2;
                    float v = acc[f][r2] * bn_scale(g[co]) + bb[co];
                    if (RES) v += bf2f(res[(size_t)(n * C_ + co) * PIX_ + p]);
                    out[(size_t)(n * C_ + co) * PIX_ + p] = v;
                }
            }
        }
    }
}

extern "C" void kernel_launch(void* const* d_in, const int* in_sizes, int n_in,
                              void* d_out, int out_size, void* d_ws, size_t ws_size,
                              hipStream_t stream) {
    const float* x       = (const float*)d_in[0];
    const float* conv1_w = (const float*)d_in[1];
    const float* bn1_g   = (const float*)d_in[2];
    const float* bn1_b   = (const float*)d_in[3];
    const float* conv2_w = (const float*)d_in[4];
    const float* bn2_g   = (const float*)d_in[5];
    const float* bn2_b   = (const float*)d_in[6];
    const float* conv3_w = (const float*)d_in[7];
    const float* bn3_g   = (const float*)d_in[8];
    const float* bn3_b   = (const float*)d_in[9];
    const float* pos_w   = (const float*)d_in[10];
    const float* bnp_g   = (const float*)d_in[11];
    const float* bnp_b   = (const float*)d_in[12];
    const float* q_w     = (const float*)d_in[13];
    const float* k_w     = (const float*)d_in[14];
    const float* v_w     = (const float*)d_in[15];
    const float* proj_w  = (const float*)d_in[16];

    float* ws = (float*)d_ws;
    unsigned short* x1    = (unsigned short*)ws;             // 3,840,000 sh (bf16 NCHW)
    unsigned short* Xc    = (unsigned short*)(ws + 7680000); // 3,840,000 sh
    unsigned short* Uall  = (unsigned short*)(ws + 9600000); // 6,031,360 sh (bf16)
    unsigned short* Oall  = (unsigned short*)(ws + 15640000);// 6,031,360 sh
    unsigned short* Aall  = (unsigned short*)(ws + 21680000);// 6,031,360 sh (bf16)
    unsigned short* Qall  = (unsigned short*)(ws + 27720000);// 6,031,360 sh
    unsigned short* Ktall = (unsigned short*)(ws + 30740000);
    unsigned short* Vall  = (unsigned short*)(ws + 33760000);// 6,045,696 sh
    unsigned short* Upall = (unsigned short*)(ws + 36790000);// 7,759,872 sh
    unsigned short* pwb   = (unsigned short*)(ws + 40670000);
    unsigned short* w2b   = (unsigned short*)(ws + 40690000);
    unsigned short* w3b   = (unsigned short*)(ws + 40856000);
    unsigned short* Xb    = (unsigned short*)(ws + 41022000);// 3,995,136 sh
    unsigned short* Xb2   = (unsigned short*)(ws + 43020000);

    x_nhwc_k<<<(N_ * 4 * PIX_ + 255) / 256, 256, 0, stream>>>(x, Xc);
    conv1x1_mfma_k<<<dim3(157, 3, 2), 256, 0, stream>>>(Xc, conv1_w, bn1_g, bn1_b, x1);
    wcvt_all_k<<<(700416 + 255) / 256, 256, 0, stream>>>(pos_w, conv2_w, conv3_w, pwb, w2b, w3b);

    gather_c_k<<<(6031360 + 255) / 256, 256, 0, stream>>>(x1, Uall);
    qkv_c_k<<<1473, 256, 0, stream>>>(Uall, q_w, k_w, v_w, Qall, Ktall, Vall);
    attn_c_k<<<2688 + 1280, 256, 0, stream>>>(Qall, Ktall, Vall, Oall);
    proj_c_k<<<1473, 256, 0, stream>>>(Oall, Uall, proj_w, Aall);
    padU_c_k<<<(121248 + 255) / 256, 256, 0, stream>>>(Uall, Upall);
    posconv_c_k<<<1473, 256, 0, stream>>>(Upall, pwb, bnp_g, bnp_b, Aall);

    ring_zero_k<<<(N_ * 404 * 192 + 255) / 256, 256, 0, stream>>>(Xb);
    fold_c_k<<<(3840000 + 255) / 256, 256, 0, stream>>>(Aall, Xb);

    ring_zero_k<<<(N_ * 404 * 192 + 255) / 256, 256, 0, stream>>>(Xb2);
    conv3x3_mfma_k<true, true><<<NB3_, 256, 0, stream>>>(
        Xb, w2b, bn2_g, bn2_b, x1, nullptr, Xb2);
    conv3x3_mfma_k<false, false><<<NB3_, 256, 0, stream>>>(
        Xb2, w3b, bn3_g, bn3_b, nullptr, (float*)d_out, nullptr);
}

// Round 25
// 246.239 us; speedup vs baseline: 1.1982x; 1.0366x over previous
//
#include <hip/hip_runtime.h>
#include <hip/hip_bf16.h>

#define N_ 2
#define C_ 192
#define CB_ 64
#define HW_ 100
#define PIX_ (HW_*HW_)
#define PADW_ 102
#define PADPIX_ (PADW_*PADW_)
#define KTOT_ 1728
#define KPOS_ 576
#define QSCALE_ 0.3606737602222409f   // 0.25 * log2(e)

typedef __attribute__((ext_vector_type(8))) short bf16x8;
typedef __attribute__((ext_vector_type(4))) short bf16x4;
typedef __attribute__((ext_vector_type(4))) float f32x4;

#if defined(__has_builtin)
#if __has_builtin(__builtin_amdgcn_mfma_f32_16x16x16bf16_1k)
#define HAVE_MFMA16 1
#endif
#if __has_builtin(__builtin_amdgcn_exp2f)
#define EXP2(x) __builtin_amdgcn_exp2f(x)
#endif
#endif
#ifndef EXP2
#define EXP2(x) exp2f(x)
#endif

static __device__ __forceinline__ float bn_scale(float g) {
    return g * rsqrtf(1.0f + 1e-5f);
}

static __device__ __forceinline__ unsigned short f2bf(float v) {
    __hip_bfloat16 h = __float2bfloat16(v);
    return *(unsigned short*)&h;
}

static __device__ __forceinline__ float bf2f(unsigned short u) {
    unsigned int v = ((unsigned int)u) << 16;
    return __uint_as_float(v);
}

// ---------------- prep: fp32 NCHW x -> bf16 channel-last [n][PIX][192] --------
__global__ __launch_bounds__(256) void x_nhwc_k(
    const float* __restrict__ in, unsigned short* __restrict__ out)
{
    int idx = blockIdx.x * 256 + threadIdx.x;
    if (idx >= N_ * 4 * PIX_) return;
    int p     = idx % PIX_;
    int chunk = (idx / PIX_) & 3;
    int n     = idx / (PIX_ * 4);
    int c0 = chunk * 48;
    const float* ip = in + ((size_t)n * C_ + c0) * PIX_ + p;
    unsigned short vals[48];
    #pragma unroll
    for (int j = 0; j < 48; ++j) vals[j] = f2bf(ip[(size_t)j * PIX_]);
    unsigned short* op = out + ((size_t)n * PIX_ + p) * 192 + c0;
    #pragma unroll
    for (int v = 0; v < 6; ++v) {
        bf16x8 pack;
        #pragma unroll
        for (int j = 0; j < 8; ++j) pack[j] = (short)vals[v * 8 + j];
        *(bf16x8*)(op + v * 8) = pack;
    }
}

// ---------------- conv1x1 + BN as GEMM, bf16 MFMA, NHWC input, bf16 out -------
__global__ __launch_bounds__(256) void conv1x1_mfma_k(
    const unsigned short* __restrict__ Xc,
    const float* __restrict__ w,
    const float* __restrict__ g, const float* __restrict__ bb,
    unsigned short* __restrict__ out)
{
    __shared__ unsigned short lds[64][72];
    int tid  = threadIdx.x;
    int lane = tid & 63;
    int wv   = tid >> 6;
    int c    = lane & 15;
    int g8   = (lane >> 4) * 8;
    int p0   = blockIdx.x * 64;
    int co0  = blockIdx.y * 64;
    int n    = blockIdx.z;

    int sp = tid >> 2;
    int sk = (tid & 3) * 8;
    int pc = min(p0 + sp, PIX_ - 1);
    const unsigned short* bp = Xc + ((size_t)n * PIX_ + pc) * 192;

    const float* arow = w + (size_t)(co0 + wv * 16 + c) * C_;

    f32x4 acc[4];
    #pragma unroll
    for (int f = 0; f < 4; ++f) acc[f] = (f32x4){0.f, 0.f, 0.f, 0.f};

    bf16x8 b0 = *(const bf16x8*)(bp + sk);
    bf16x8 b1 = *(const bf16x8*)(bp + 32 + sk);

    for (int k0 = 0; k0 < C_; k0 += 64) {
        __syncthreads();
        *(bf16x8*)(&lds[sp][sk])      = b0;
        *(bf16x8*)(&lds[sp][32 + sk]) = b1;
        __syncthreads();
        if (k0 + 64 < C_) {
            b0 = *(const bf16x8*)(bp + k0 + 64 + sk);
            b1 = *(const bf16x8*)(bp + k0 + 96 + sk);
        }
        #pragma unroll
        for (int h = 0; h < 2; ++h) {
            bf16x8 a;
            const float* ap = arow + k0 + h * 32 + g8;
            #pragma unroll
            for (int j = 0; j < 8; ++j) a[j] = (short)f2bf(ap[j]);
            #pragma unroll
            for (int f = 0; f < 4; ++f) {
                bf16x8 b = *(const bf16x8*)(&lds[f * 16 + c][h * 32 + g8]);
                acc[f] = __builtin_amdgcn_mfma_f32_16x16x32_bf16(a, b, acc[f], 0, 0, 0);
            }
        }
    }

    #pragma unroll
    for (int f = 0; f < 4; ++f) {
        int p = p0 + f * 16 + c;
        if (p < PIX_) {
            #pragma unroll
            for (int r = 0; r < 4; ++r) {
                int co = co0 + wv * 16 + (lane >> 4) * 4 + r;
                out[(size_t)(n * C_ + co) * PIX_ + p] =
                    f2bf(acc[f][r] * bn_scale(g[co]) + bb[co]);
            }
        }
    }
}

// ---------------- combined weight converts (pos + conv2 + conv3) -------------
__global__ __launch_bounds__(256) void wcvt_all_k(
    const float* __restrict__ pw, const float* __restrict__ w2,
    const float* __restrict__ w3,
    unsigned short* __restrict__ pwb, unsigned short* __restrict__ w2b,
    unsigned short* __restrict__ w3b)
{
    int idx = blockIdx.x * 256 + threadIdx.x;
    const int S0 = CB_ * KPOS_;          // 36864
    const int S1 = S0 + C_ * KTOT_;      // 368640
    const int S2 = S1 + C_ * KTOT_;      // 700416
    if (idx < S0) {
        int t = idx % 9, ci = (idx / 9) % CB_, co = idx / (9 * CB_);
        pwb[(size_t)co * KPOS_ + t * CB_ + ci] = f2bf(pw[idx]);
    } else if (idx < S1) {
        int k = idx - S0;
        int t = k % 9, ci = (k / 9) % C_, co = k / (9 * C_);
        w2b[(size_t)co * KTOT_ + t * C_ + ci] = f2bf(w2[k]);
    } else if (idx < S2) {
        int k = idx - S1;
        int t = k % 9, ci = (k / 9) % C_, co = k / (9 * C_);
        w3b[(size_t)co * KTOT_ + t * C_ + ci] = f2bf(w3[k]);
    }
}

// ---------------- combined gather (all 3 chunks), bf16 in/out -----------------
template<int NW, int SH, int KH>
__device__ __forceinline__ void gather_body(
    const unsigned short* __restrict__ x1, unsigned short* __restrict__ U,
    int f, int cidx)
{
    int t = f;
    int j = t % NW; t /= NW;
    int i = t % NW; t /= NW;
    int c = t % KH; t /= KH;
    int r = t % KH; t /= KH;
    int cb = t % CB_;
    int n  = t / CB_;
    int hh = i * SH + r;
    int ww = j * SH + c;
    U[f] = x1[((n * C_ + cidx * CB_ + cb) * HW_ + hh) * HW_ + ww];
}

__global__ __launch_bounds__(256) void gather_c_k(
    const unsigned short* __restrict__ x1, unsigned short* __restrict__ Uall)
{
    int gid = blockIdx.x * 256 + threadIdx.x;
    if (gid < 1280000)       gather_body<4, 25, 25>(x1, Uall,            gid,            0);
    else if (gid < 3377152)  gather_body<8, 12, 16>(x1, Uall + 1280000,  gid - 1280000,  1);
    else if (gid < 6031360)  gather_body<12, 8, 12>(x1, Uall + 3377152,  gid - 3377152,  2);
}

// ---------------- fused q/k/v GEMM body (templated L), bf16 U -----------------
template<int L, int LP, int NPIX>
__device__ __forceinline__ void qkv_body(
    unsigned short (*lds)[72],
    const unsigned short* __restrict__ U,
    const float* __restrict__ qw, const float* __restrict__ kw,
    const float* __restrict__ vw,
    unsigned short* __restrict__ Q, unsigned short* __restrict__ Kt,
    unsigned short* __restrict__ V, int bid)
{
    int tid  = threadIdx.x;
    int lane = tid & 63;
    int wv   = tid >> 6;
    int c    = lane & 15;
    int g8   = (lane >> 4) * 8;
    int q0   = bid * 64;

    int sp = tid >> 2;
    int sk = (tid & 3) * 8;
    int qc = min(q0 + sp, NPIX - 1);
    int b  = qc / L, p = qc % L;
    const unsigned short* ub = U + (size_t)b * 64 * L + p;

    bf16x8 b0, b1;
    #pragma unroll
    for (int j = 0; j < 8; ++j) {
        b0[j] = (short)ub[(size_t)(sk + j) * L];
        b1[j] = (short)ub[(size_t)(32 + sk + j) * L];
    }
    __syncthreads();
    *(bf16x8*)(&lds[sp][sk])      = b0;
    *(bf16x8*)(&lds[sp][32 + sk]) = b1;
    __syncthreads();

    f32x4 acc[3][4];
    #pragma unroll
    for (int s = 0; s < 3; ++s)
        #pragma unroll
        for (int f = 0; f < 4; ++f) acc[s][f] = (f32x4){0.f, 0.f, 0.f, 0.f};

    const float* wbase[3] = {qw, kw, vw};
    #pragma unroll
    for (int s = 0; s < 3; ++s) {
        const float* arow = wbase[s] + (size_t)(wv * 16 + c) * 64;
        #pragma unroll
        for (int h = 0; h < 2; ++h) {
            bf16x8 a;
            const float* ap = arow + h * 32 + g8;
            #pragma unroll
            for (int j = 0; j < 8; ++j) a[j] = (short)f2bf(ap[j]);
            #pragma unroll
            for (int f = 0; f < 4; ++f) {
                bf16x8 bfr = *(const bf16x8*)(&lds[f * 16 + c][h * 32 + g8]);
                acc[s][f] = __builtin_amdgcn_mfma_f32_16x16x32_bf16(a, bfr, acc[s][f], 0, 0, 0);
            }
        }
    }

    #pragma unroll
    for (int f = 0; f < 4; ++f) {
        int qq = q0 + f * 16 + c;
        if (qq < NPIX) {
            int bo = qq / L, po = qq % L;
            #pragma unroll
            for (int r = 0; r < 4; ++r) {
                int co = wv * 16 + (lane >> 4) * 4 + r;
                Q[(size_t)(bo * 64 + co) * L + po] = f2bf(acc[0][f][r] * QSCALE_);
                Kt[((size_t)(bo * 4 + wv) * L + po) * 16 + ((lane >> 4) * 4 + r)] = f2bf(acc[1][f][r]);
                V[(size_t)(bo * 64 + co) * LP + po] = f2bf(acc[2][f][r]);
            }
        }
    }
}

__global__ __launch_bounds__(256) void qkv_c_k(
    const unsigned short* __restrict__ Uall,
    const float* __restrict__ qw, const float* __restrict__ kw,
    const float* __restrict__ vw,
    unsigned short* __restrict__ Qa, unsigned short* __restrict__ Ka,
    unsigned short* __restrict__ Va)
{
    __shared__ unsigned short lds[64][72];
    int bid = blockIdx.x;
    if (bid < 313)
        qkv_body<625, 632, 20000>(lds, Uall, qw, kw, vw, Qa, Ka, Va, bid);
    else if (bid < 825)
        qkv_body<256, 256, 32768>(lds, Uall + 1280000, qw, kw, vw,
                                  Qa + 1280000, Ka + 1280000, Va + 1294336, bid - 313);
    else
        qkv_body<144, 144, 41472>(lds, Uall + 3377152, qw, kw, vw,
                                  Qa + 3377152, Ka + 3377152, Va + 3391488, bid - 825);
}

// ---------------- attention tile body (MASK only for the tail tile) -----------
template<int L, int LP, bool MASK>
__device__ __forceinline__ void attn_tile(
    int m0, const unsigned short* __restrict__ kb,
    const unsigned short* __restrict__ vb, int c, int g,
#ifdef HAVE_MFMA16
    const bf16x4* qf,
#else
    const bf16x8* qf,
#endif
    f32x4* acc, float* mrun, float* srun)
{
    float p[2][16];
#ifdef HAVE_MFMA16
    #pragma unroll
    for (int t = 0; t < 4; ++t) {
        int mm = m0 + c + t * 16;
        if (MASK) mm = min(mm, L - 1);
        bf16x4 kf = *(const bf16x4*)(kb + (size_t)mm * 16 + g * 4);   // shared
        f32x4 s0 = __builtin_amdgcn_mfma_f32_16x16x16bf16_1k(
            kf, qf[0], (f32x4){0.f,0.f,0.f,0.f}, 0, 0, 0);
        f32x4 s1 = __builtin_amdgcn_mfma_f32_16x16x16bf16_1k(
            kf, qf[1], (f32x4){0.f,0.f,0.f,0.f}, 0, 0, 0);
        #pragma unroll
        for (int r = 0; r < 4; ++r) {
            p[0][t * 4 + r] = s0[r];
            p[1][t * 4 + r] = s1[r];
        }
    }
#else
    #pragma unroll
    for (int t = 0; t < 4; ++t) {
        bf16x8 kf = (bf16x8){0,0,0,0,0,0,0,0};
        if (g < 2) {
            int mm = m0 + c + t * 16;
            if (MASK) mm = min(mm, L - 1);
            kf = *(const bf16x8*)(kb + (size_t)mm * 16 + g * 8);
        }
        f32x4 s0 = __builtin_amdgcn_mfma_f32_16x16x32_bf16(
            kf, qf[0], (f32x4){0.f,0.f,0.f,0.f}, 0, 0, 0);
        f32x4 s1 = __builtin_amdgcn_mfma_f32_16x16x32_bf16(
            kf, qf[1], (f32x4){0.f,0.f,0.f,0.f}, 0, 0, 0);
        #pragma unroll
        for (int r = 0; r < 4; ++r) {
            p[0][t * 4 + r] = s0[r];
            p[1][t * 4 + r] = s1[r];
        }
    }
#endif

    #pragma unroll
    for (int ch = 0; ch < 2; ++ch) {
        float tmax = -1e30f;
        #pragma unroll
        for (int t = 0; t < 4; ++t) {
            #pragma unroll
            for (int r = 0; r < 4; ++r) {
                float v = p[ch][t * 4 + r];
                if (MASK) {
                    int m = m0 + t * 16 + g * 4 + r;
                    if (m >= L) v = -1e30f;
                    p[ch][t * 4 + r] = v;
                }
                tmax = fmaxf(tmax, v);
            }
        }
        tmax = fmaxf(tmax, __shfl_xor(tmax, 16, 64));
        tmax = fmaxf(tmax, __shfl_xor(tmax, 32, 64));
        if (!__all(tmax <= mrun[ch])) {
            float mnew = fmaxf(mrun[ch], tmax);
            float corr = EXP2(mrun[ch] - mnew);
            srun[ch] *= corr;
            #pragma unroll
            for (int r = 0; r < 4; ++r) acc[ch][r] *= corr;
            mrun[ch] = mnew;
        }
        float ps0 = 0.f, ps1 = 0.f, ps2 = 0.f, ps3 = 0.f;
        #pragma unroll
        for (int t = 0; t < 4; ++t) {
            p[ch][t * 4 + 0] = EXP2(p[ch][t * 4 + 0] - mrun[ch]); ps0 += p[ch][t * 4 + 0];
            p[ch][t * 4 + 1] = EXP2(p[ch][t * 4 + 1] - mrun[ch]); ps1 += p[ch][t * 4 + 1];
            p[ch][t * 4 + 2] = EXP2(p[ch][t * 4 + 2] - mrun[ch]); ps2 += p[ch][t * 4 + 2];
            p[ch][t * 4 + 3] = EXP2(p[ch][t * 4 + 3] - mrun[ch]); ps3 += p[ch][t * 4 + 3];
        }
        srun[ch] += (ps0 + ps1) + (ps2 + ps3);
    }

#ifdef HAVE_MFMA16
    #pragma unroll
    for (int t = 0; t < 4; ++t) {
        bf16x4 vf = *(const bf16x4*)(vb + m0 + t * 16 + g * 4);           // shared
        bf16x4 pb0, pb1;
        #pragma unroll
        for (int j = 0; j < 4; ++j) {
            pb0[j] = (short)f2bf(p[0][t * 4 + j]);
            pb1[j] = (short)f2bf(p[1][t * 4 + j]);
        }
        acc[0] = __builtin_amdgcn_mfma_f32_16x16x16bf16_1k(vf, pb0, acc[0], 0, 0, 0);
        acc[1] = __builtin_amdgcn_mfma_f32_16x16x16bf16_1k(vf, pb1, acc[1], 0, 0, 0);
    }
#else
    int hi = g >> 1;
    #pragma unroll
    for (int H = 0; H < 2; ++H) {
        bf16x8 vf = *(const bf16x8*)(vb + m0 + H * 32 + g * 8);           // shared
        #pragma unroll
        for (int ch = 0; ch < 2; ++ch) {
            bf16x8 pb;
            #pragma unroll
            for (int j = 0; j < 8; ++j) {
                int srcLane = (((2 * g + (j >> 2)) & 3) << 4) | c;
                float v1 = __shfl(p[ch][(H * 2) * 4 + (j & 3)], srcLane, 64);
                float v2 = __shfl(p[ch][(H * 2 + 1) * 4 + (j & 3)], srcLane, 64);
                pb[j] = (short)f2bf(hi ? v2 : v1);
            }
            acc[ch] = __builtin_amdgcn_mfma_f32_16x16x32_bf16(vf, pb, acc[ch], 0, 0, 0);
        }
    }
#endif
}

// ---------------- MFMA flash attention: 2 query-chains per wave ---------------
template<int L, int LP>
__device__ __forceinline__ void attn_body(
    const unsigned short* __restrict__ Q, const unsigned short* __restrict__ Kt,
    const unsigned short* __restrict__ V, unsigned short* __restrict__ O,
    int lblk, int bh)
{
    constexpr int NFULL = L / 64;
    constexpr int TAIL  = L % 64;

    int tid  = threadIdx.x;
    int lane = tid & 63;
    int wv   = tid >> 6;
    int c    = lane & 15;
    int g    = lane >> 4;
    int b = bh >> 2, h = bh & 3;
    const unsigned short* qb = Q + (size_t)(b * 64 + h * 16) * L;
    const unsigned short* kb = Kt + (size_t)bh * L * 16;
    const unsigned short* vb = V + (size_t)(b * 64 + h * 16) * LP + (size_t)c * LP;
    unsigned short* ob = O + (size_t)(b * 64 + h * 16) * L;

    int lbase = lblk * 128 + wv * 16 + c;
    int l[2] = {lbase, lbase + 64};
    bool lval[2];
    int lc[2];
    #pragma unroll
    for (int ch = 0; ch < 2; ++ch) {
        lval[ch] = (l[ch] < L);
        lc[ch] = lval[ch] ? l[ch] : (L - 1);
    }

    f32x4 acc[2];
    float mrun[2], srun[2];
    #pragma unroll
    for (int ch = 0; ch < 2; ++ch) {
        acc[ch] = (f32x4){0.f, 0.f, 0.f, 0.f};
        mrun[ch] = -1e30f; srun[ch] = 0.f;
    }

#ifdef HAVE_MFMA16
    bf16x4 qf[2];
    #pragma unroll
    for (int ch = 0; ch < 2; ++ch)
        #pragma unroll
        for (int j = 0; j < 4; ++j) qf[ch][j] = (short)qb[(g * 4 + j) * L + lc[ch]];
#else
    bf16x8 qf[2];
    #pragma unroll
    for (int ch = 0; ch < 2; ++ch) {
        qf[ch] = (bf16x8){0,0,0,0,0,0,0,0};
        if (g < 2) {
            #pragma unroll
            for (int j = 0; j < 8; ++j) qf[ch][j] = (short)qb[(g * 8 + j) * L + lc[ch]];
        }
    }
#endif

    for (int mt = 0; mt < NFULL; ++mt)
        attn_tile<L, LP, false>(mt * 64, kb, vb, c, g, qf, acc, mrun, srun);
    if (TAIL > 0)
        attn_tile<L, LP, true>(NFULL * 64, kb, vb, c, g, qf, acc, mrun, srun);

    #pragma unroll
    for (int ch = 0; ch < 2; ++ch) {
        float stot = srun[ch];
        stot += __shfl_xor(stot, 16, 64);
        stot += __shfl_xor(stot, 32, 64);
        float inv = 1.f / stot;
        if (lval[ch]) {
            #pragma unroll
            for (int r = 0; r < 4; ++r)
                ob[(size_t)(g * 4 + r) * L + l[ch]] = f2bf(acc[ch][r] * inv);
        }
    }
}

__global__ __launch_bounds__(256) void attn_c_k(
    const unsigned short* __restrict__ Qa, const unsigned short* __restrict__ Ka,
    const unsigned short* __restrict__ Va, unsigned short* __restrict__ Oa)
{
    int bid = blockIdx.x;
    if (bid < 640) {                               // chunk0: 5 lblk x 128 bh
        attn_body<625, 632>(Qa, Ka, Va, Oa, bid % 5, bid / 5);
    } else if (bid < 1664) {                       // chunk1: 2 lblk x 512 bh
        int k = bid - 640;
        attn_body<256, 256>(Qa + 1280000, Ka + 1280000, Va + 1294336,
                            Oa + 1280000, k % 2, k / 2);
    } else {                                       // chunk2: 2 lblk x 1152 bh
        int k = bid - 1664;
        attn_body<144, 144>(Qa + 3377152, Ka + 3377152, Va + 3391488,
                            Oa + 3377152, k % 2, k / 2);
    }
}

// ---------------- padU body (templated), bf16 U input -------------------------
template<int KH, int PW, int L>
__device__ __forceinline__ void padU_body(
    const unsigned short* __restrict__ U, unsigned short* __restrict__ Up, int idx)
{
    int pp = idx % (PW * PW);
    int b  = idx / (PW * PW);
    int xx = pp % PW, yy = pp / PW;
    bool inter = (xx >= 1 && xx <= KH && yy >= 1 && yy <= KH);
    const unsigned short* up = U + (size_t)b * 64 * L + (yy - 1) * KH + (xx - 1);
    unsigned short vals[64];
    #pragma unroll
    for (int j = 0; j < 64; ++j) vals[j] = inter ? up[(size_t)j * L] : 0;
    unsigned short* op = Up + (size_t)idx * 64;
    #pragma unroll
    for (int v = 0; v < 8; ++v) {
        bf16x8 pack;
        #pragma unroll
        for (int j = 0; j < 8; ++j) pack[j] = (short)vals[v * 8 + j];
        *(bf16x8*)(op + v * 8) = pack;
    }
}

__global__ __launch_bounds__(256) void padU_c_k(
    const unsigned short* __restrict__ Uall, unsigned short* __restrict__ Upa)
{
    int idx = blockIdx.x * 256 + threadIdx.x;
    if (idx < 23328)        padU_body<25, 27, 625>(Uall,            Upa,            idx);
    else if (idx < 64800)   padU_body<16, 18, 256>(Uall + 1280000,  Upa + 1492992,  idx - 23328);
    else if (idx < 121248)  padU_body<12, 14, 144>(Uall + 3377152,  Upa + 4147200,  idx - 64800);
}

// ---------------- FUSED proj + residual + posconv + BN -> bf16 A --------------
// Phase 1: proj GEMM (O staged in lds[0], K=64).
// Phase 2: posconv 9-tap GEMM (dbuf over lds[0]/lds[1]).
// Epilogue: A = f2bf(projAcc + U + posAcc*bn + b), single write, no A read.
template<int L, int PW, int KH, int NPIX>
__device__ __forceinline__ void projpos_body(
    unsigned short (*lds)[64][72],
    const unsigned short* __restrict__ O, const unsigned short* __restrict__ U,
    const unsigned short* __restrict__ Up,
    const float* __restrict__ pw, const unsigned short* __restrict__ Wb,
    const float* __restrict__ g, const float* __restrict__ bb,
    unsigned short* __restrict__ A, int bid)
{
    int tid  = threadIdx.x;
    int lane = tid & 63;
    int wv   = tid >> 6;
    int c    = lane & 15;
    int g8   = (lane >> 4) * 8;
    int p0   = bid * 64;

    int sp = tid >> 2;
    int sk = (tid & 3) * 8;
    int qc = min(p0 + sp, NPIX - 1);
    int b  = qc / L, p = qc % L;

    // -------- phase 1: proj GEMM --------
    {
        const unsigned short* ob = O + (size_t)b * 64 * L + p;
        bf16x8 t0, t1;
        #pragma unroll
        for (int j = 0; j < 8; ++j) {
            t0[j] = (short)ob[(size_t)(sk + j) * L];
            t1[j] = (short)ob[(size_t)(32 + sk + j) * L];
        }
        *(bf16x8*)(&lds[0][sp][sk])      = t0;
        *(bf16x8*)(&lds[0][sp][32 + sk]) = t1;
    }
    __syncthreads();

    f32x4 accP[4];
    #pragma unroll
    for (int f = 0; f < 4; ++f) accP[f] = (f32x4){0.f, 0.f, 0.f, 0.f};
    {
        const float* prow = pw + (size_t)(wv * 16 + c) * 64;
        #pragma unroll
        for (int h = 0; h < 2; ++h) {
            bf16x8 a;
            const float* ap = prow + h * 32 + g8;
            #pragma unroll
            for (int j = 0; j < 8; ++j) a[j] = (short)f2bf(ap[j]);
            #pragma unroll
            for (int f = 0; f < 4; ++f) {
                bf16x8 bfr = *(const bf16x8*)(&lds[0][f * 16 + c][h * 32 + g8]);
                accP[f] = __builtin_amdgcn_mfma_f32_16x16x32_bf16(a, bfr, accP[f], 0, 0, 0);
            }
        }
    }
    __syncthreads();   // all proj LDS reads done before posconv overwrites lds[0]

    // -------- phase 2: posconv GEMM (9 taps, LDS dbuf) --------
    int po = b * PW * PW + (p / KH) * PW + (p % KH);

    const unsigned short* arow = Wb + (size_t)(wv * 16 + c) * KPOS_;

    f32x4 accC[4];
    #pragma unroll
    for (int f = 0; f < 4; ++f) accC[f] = (f32x4){0.f, 0.f, 0.f, 0.f};

    const int NT = KPOS_ / 64;                // 9

    bf16x8 b0, b1, a0, a1;
    {
        const unsigned short* bp = Up + ((size_t)po << 6);
        b0 = *(const bf16x8*)(bp + sk);
        b1 = *(const bf16x8*)(bp + 32 + sk);
        *(bf16x8*)(&lds[0][sp][sk])      = b0;
        *(bf16x8*)(&lds[0][sp][32 + sk]) = b1;
    }
    {
        const unsigned short* bp = Up + ((size_t)(po + 1) << 6);  // tap 1
        b0 = *(const bf16x8*)(bp + sk);
        b1 = *(const bf16x8*)(bp + 32 + sk);
    }
    a0 = *(const bf16x8*)(arow + g8);
    a1 = *(const bf16x8*)(arow + 32 + g8);

    for (int t = 0; t < NT; ++t) {
        __syncthreads();
        bf16x8 bf0[4], bf1[4];
        #pragma unroll
        for (int f = 0; f < 4; ++f) {
            bf0[f] = *(const bf16x8*)(&lds[t & 1][f * 16 + c][g8]);
            bf1[f] = *(const bf16x8*)(&lds[t & 1][f * 16 + c][32 + g8]);
        }
        if (t + 1 < NT) {
            *(bf16x8*)(&lds[(t + 1) & 1][sp][sk])      = b0;
            *(bf16x8*)(&lds[(t + 1) & 1][sp][32 + sk]) = b1;
            if (t + 2 < NT) {
                int tap = t + 2;
                int toff = (tap / 3) * PW + (tap % 3);
                const unsigned short* bp = Up + ((size_t)(po + toff) << 6);
                b0 = *(const bf16x8*)(bp + sk);
                b1 = *(const bf16x8*)(bp + 32 + sk);
            }
        }
        bf16x8 a0n, a1n;
        if (t + 1 < NT) {
            a0n = *(const bf16x8*)(arow + (t + 1) * 64 + g8);
            a1n = *(const bf16x8*)(arow + (t + 1) * 64 + 32 + g8);
        }
        #pragma unroll
        for (int f = 0; f < 4; ++f) {
            accC[f] = __builtin_amdgcn_mfma_f32_16x16x32_bf16(a0, bf0[f], accC[f], 0, 0, 0);
            accC[f] = __builtin_amdgcn_mfma_f32_16x16x32_bf16(a1, bf1[f], accC[f], 0, 0, 0);
        }
        a0 = a0n; a1 = a1n;
    }

    // -------- epilogue: single A write --------
    #pragma unroll
    for (int f = 0; f < 4; ++f) {
        int q = p0 + f * 16 + c;
        if (q < NPIX) {
            int bo = q / L, pp = q % L;
            #pragma unroll
            for (int r = 0; r < 4; ++r) {
                int co = wv * 16 + (lane >> 4) * 4 + r;
                size_t ai = (size_t)(bo * 64 + co) * L + pp;
                A[ai] = f2bf(accP[f][r] + bf2f(U[ai]) +
                             accC[f][r] * bn_scale(g[co]) + bb[co]);
            }
        }
    }
}

__global__ __launch_bounds__(256) void projpos_c_k(
    const unsigned short* __restrict__ Oa, const unsigned short* __restrict__ Uall,
    const unsigned short* __restrict__ Upa,
    const float* __restrict__ pw, const unsigned short* __restrict__ Wb,
    const float* __restrict__ g, const float* __restrict__ bb,
    unsigned short* __restrict__ Aa)
{
    __shared__ unsigned short lds[2][64][72];
    int bid = blockIdx.x;
    if (bid < 313)
        projpos_body<625, 27, 25, 20000>(lds, Oa, Uall, Upa, pw, Wb, g, bb, Aa, bid);
    else if (bid < 825)
        projpos_body<256, 18, 16, 32768>(lds, Oa + 1280000, Uall + 1280000,
                                         Upa + 1492992, pw, Wb, g, bb,
                                         Aa + 1280000, bid - 313);
    else
        projpos_body<144, 14, 12, 41472>(lds, Oa + 3377152, Uall + 3377152,
                                         Upa + 4147200, pw, Wb, g, bb,
                                         Aa + 3377152, bid - 825);
}

// ---------------- fold body: bf16 A -> conv2's NHWC bf16 input ----------------
template<int NW, int SH, int KH>
__device__ __forceinline__ void fold_body(
    const unsigned short* __restrict__ A, unsigned short* __restrict__ Xb,
    int idx, int cidx)
{
    int w  = idx % HW_;
    int h  = (idx / HW_) % HW_;
    int cb = (idx / PIX_) % CB_;
    int n  = idx / (PIX_ * CB_);
    int numh = h - KH + 1;
    int ilo = numh > 0 ? (numh + SH - 1) / SH : 0;
    int ihi = min(NW - 1, h / SH);
    int numw = w - KH + 1;
    int jlo = numw > 0 ? (numw + SH - 1) / SH : 0;
    int jhi = min(NW - 1, w / SH);
    float sum = 0.f;
    for (int i = ilo; i <= ihi; ++i) {
        int r = h - i * SH;
        for (int j = jlo; j <= jhi; ++j) {
            int c = w - j * SH;
            int f = ((((n * CB_ + cb) * KH + r) * KH + c) * NW + i) * NW + j;
            sum += bf2f(A[f]);
        }
    }
    float cnt = (float)((ihi - ilo + 1) * (jhi - jlo + 1));
    Xb[((size_t)n * PADPIX_ + (h + 1) * PADW_ + (w + 1)) * 192 + cidx * CB_ + cb]
        = f2bf(sum / cnt);
}

__global__ __launch_bounds__(256) void fold_c_k(
    const unsigned short* __restrict__ Aa, unsigned short* __restrict__ Xb)
{
    int idx = blockIdx.x * 256 + threadIdx.x;
    if (idx < 1280000)       fold_body<4, 25, 25>(Aa,            Xb, idx,            0);
    else if (idx < 2560000)  fold_body<8, 12, 16>(Aa + 1280000,  Xb, idx - 1280000,  1);
    else if (idx < 3840000)  fold_body<12, 8, 12>(Aa + 3377152,  Xb, idx - 2560000,  2);
}

// ---------------- prep: zero pad ring of BOTH NHWC buffers --------------------
__global__ __launch_bounds__(256) void ring_zero2_k(
    unsigned short* __restrict__ Xb, unsigned short* __restrict__ Xb2)
{
    int idx = blockIdx.x * 256 + threadIdx.x;
    const int T = N_ * 404 * 192;
    if (idx >= 2 * T) return;
    unsigned short* dst = (idx < T) ? Xb : Xb2;
    int k = (idx < T) ? idx : idx - T;
    int cc = k % 192;
    int rp = (k / 192) % 404;
    int n  = k / (192 * 404);
    int yy, xx;
    if (rp < 102)      { yy = 0;            xx = rp; }
    else if (rp < 204) { yy = 101;          xx = rp - 102; }
    else if (rp < 304) { yy = rp - 204 + 1; xx = 0; }
    else               { yy = rp - 304 + 1; xx = 101; }
    dst[((size_t)n * PADPIX_ + yy * PADW_ + xx) * 192 + cc] = 0;
}

// ---------------- 3x3 conv implicit GEMM, NHWC bf16, XCD swizzle + LDS dbuf ---
// RES reads bf16 residual; TOXB writes NHWC bf16 (conv3's input).
#define NB3_ (157*3*2)
template<bool RES, bool TOXB>
__global__ __launch_bounds__(256) void conv3x3_mfma_k(
    const unsigned short* __restrict__ Xp,
    const unsigned short* __restrict__ Wb,
    const float* __restrict__ g, const float* __restrict__ bb,
    const unsigned short* __restrict__ res, float* __restrict__ out,
    unsigned short* __restrict__ xout)
{
    __shared__ unsigned short lds[2][64][72];
    int tid  = threadIdx.x;
    int lane = tid & 63;
    int wv   = tid >> 6;
    int c    = lane & 15;
    int g8   = (lane >> 4) * 8;

    const int q = NB3_ / 8, r = NB3_ % 8;
    int gid  = blockIdx.x;
    int xcd  = gid % 8, slot = gid / 8;
    int wgid = (xcd < r) ? xcd * (q + 1) + slot
                         : r * (q + 1) + (xcd - r) * q + slot;
    int co0  = (wgid % 3) * 64;
    int rest = wgid / 3;
    int p0   = (rest % 157) * 64;
    int n    = rest / 157;

    const unsigned short* Xn = Xp + (size_t)n * PADPIX_ * 192;

    int sp = tid >> 2;
    int sk = (tid & 3) * 8;
    int pix = p0 + sp;
    int po = (pix < PIX_) ? (pix / HW_) * PADW_ + (pix % HW_) : 0;

    const unsigned short* arow = Wb + (size_t)(co0 + wv * 16 + c) * KTOT_;

    f32x4 acc[4];
    #pragma unroll
    for (int f = 0; f < 4; ++f) acc[f] = (f32x4){0.f, 0.f, 0.f, 0.f};

    const int NT = KTOT_ / 64;

    bf16x8 b0, b1, a0, a1;
    {
        const unsigned short* bp = Xn + (size_t)po * 192;
        b0 = *(const bf16x8*)(bp + sk);
        b1 = *(const bf16x8*)(bp + 32 + sk);
        *(bf16x8*)(&lds[0][sp][sk])      = b0;
        *(bf16x8*)(&lds[0][sp][32 + sk]) = b1;
    }
    {
        const unsigned short* bp = Xn + (size_t)po * 192 + 64;
        b0 = *(const bf16x8*)(bp + sk);
        b1 = *(const bf16x8*)(bp + 32 + sk);
    }
    a0 = *(const bf16x8*)(arow + g8);
    a1 = *(const bf16x8*)(arow + 32 + g8);

    for (int t = 0; t < NT; ++t) {
        __syncthreads();
        bf16x8 bf0[4], bf1[4];
        #pragma unroll
        for (int f = 0; f < 4; ++f) {
            bf0[f] = *(const bf16x8*)(&lds[t & 1][f * 16 + c][g8]);
            bf1[f] = *(const bf16x8*)(&lds[t & 1][f * 16 + c][32 + g8]);
        }
        if (t + 1 < NT) {
            *(bf16x8*)(&lds[(t + 1) & 1][sp][sk])      = b0;
            *(bf16x8*)(&lds[(t + 1) & 1][sp][32 + sk]) = b1;
            if (t + 2 < NT) {
                int k2 = (t + 2) * 64;
                int tap = k2 / 192;
                int ci0 = k2 - tap * 192;
                int toff = (tap / 3) * PADW_ + (tap % 3);
                const unsigned short* bp = Xn + (size_t)(po + toff) * 192 + ci0;
                b0 = *(const bf16x8*)(bp + sk);
                b1 = *(const bf16x8*)(bp + 32 + sk);
            }
        }
        bf16x8 a0n, a1n;
        if (t + 1 < NT) {
            a0n = *(const bf16x8*)(arow + (t + 1) * 64 + g8);
            a1n = *(const bf16x8*)(arow + (t + 1) * 64 + 32 + g8);
        }
        #pragma unroll
        for (int f = 0; f < 4; ++f) {
            acc[f] = __builtin_amdgcn_mfma_f32_16x16x32_bf16(a0, bf0[f], acc[f], 0, 0, 0);
            acc[f] = __builtin_amdgcn_mfma_f32_16x16x32_bf16(a1, bf1[f], acc[f], 0, 0, 0);
        }
        a0 = a0n; a1 = a1n;
    }

    #pragma unroll
    for (int f = 0; f < 4; ++f) {
        int p = p0 + f * 16 + c;
        if (p < PIX_) {
            if (TOXB) {
                int py = p / HW_, px = p % HW_;
                unsigned short* o = xout +
                    ((size_t)n * PADPIX_ + (py + 1) * PADW_ + (px + 1)) * 192 +
                    co0 + wv * 16 + (lane >> 4) * 4;
                ushort4 pk;
                #pragma unroll
                for (int r2 = 0; r2 < 4; ++r2) {
                    int co = co0 + wv * 16 + (lane >> 4) * 4 + r2;
                    float v = acc[f][r2] * bn_scale(g[co]) + bb[co];
                    if (RES) v += bf2f(res[(size_t)(n * C_ + co) * PIX_ + p]);
                    ((unsigned short*)&pk)[r2] = f2bf(v);
                }
                *(ushort4*)o = pk;
            } else {
                #pragma unroll
                for (int r2 = 0; r2 < 4; ++r2) {
                    int co = co0 + wv * 16 + (lane >> 4) * 4 + r2;
                    float v = acc[f][r2] * bn_scale(g[co]) + bb[co];
                    if (RES) v += bf2f(res[(size_t)(n * C_ + co) * PIX_ + p]);
                    out[(size_t)(n * C_ + co) * PIX_ + p] = v;
                }
            }
        }
    }
}

extern "C" void kernel_launch(void* const* d_in, const int* in_sizes, int n_in,
                              void* d_out, int out_size, void* d_ws, size_t ws_size,
                              hipStream_t stream) {
    const float* x       = (const float*)d_in[0];
    const float* conv1_w = (const float*)d_in[1];
    const float* bn1_g   = (const float*)d_in[2];
    const float* bn1_b   = (const float*)d_in[3];
    const float* conv2_w = (const float*)d_in[4];
    const float* bn2_g   = (const float*)d_in[5];
    const float* bn2_b   = (const float*)d_in[6];
    const float* conv3_w = (const float*)d_in[7];
    const float* bn3_g   = (const float*)d_in[8];
    const float* bn3_b   = (const float*)d_in[9];
    const float* pos_w   = (const float*)d_in[10];
    const float* bnp_g   = (const float*)d_in[11];
    const float* bnp_b   = (const float*)d_in[12];
    const float* q_w     = (const float*)d_in[13];
    const float* k_w     = (const float*)d_in[14];
    const float* v_w     = (const float*)d_in[15];
    const float* proj_w  = (const float*)d_in[16];

    float* ws = (float*)d_ws;
    unsigned short* x1    = (unsigned short*)ws;             // 3,840,000 sh (bf16 NCHW)
    unsigned short* Xc    = (unsigned short*)(ws + 7680000); // 3,840,000 sh
    unsigned short* Uall  = (unsigned short*)(ws + 9600000); // 6,031,360 sh (bf16)
    unsigned short* Oall  = (unsigned short*)(ws + 15640000);// 6,031,360 sh
    unsigned short* Aall  = (unsigned short*)(ws + 21680000);// 6,031,360 sh (bf16)
    unsigned short* Qall  = (unsigned short*)(ws + 27720000);// 6,031,360 sh
    unsigned short* Ktall = (unsigned short*)(ws + 30740000);
    unsigned short* Vall  = (unsigned short*)(ws + 33760000);// 6,045,696 sh
    unsigned short* Upall = (unsigned short*)(ws + 36790000);// 7,759,872 sh
    unsigned short* pwb   = (unsigned short*)(ws + 40670000);
    unsigned short* w2b   = (unsigned short*)(ws + 40690000);
    unsigned short* w3b   = (unsigned short*)(ws + 40856000);
    unsigned short* Xb    = (unsigned short*)(ws + 41022000);// 3,995,136 sh
    unsigned short* Xb2   = (unsigned short*)(ws + 43020000);

    x_nhwc_k<<<(N_ * 4 * PIX_ + 255) / 256, 256, 0, stream>>>(x, Xc);
    conv1x1_mfma_k<<<dim3(157, 3, 2), 256, 0, stream>>>(Xc, conv1_w, bn1_g, bn1_b, x1);
    wcvt_all_k<<<(700416 + 255) / 256, 256, 0, stream>>>(pos_w, conv2_w, conv3_w, pwb, w2b, w3b);

    gather_c_k<<<(6031360 + 255) / 256, 256, 0, stream>>>(x1, Uall);
    qkv_c_k<<<1473, 256, 0, stream>>>(Uall, q_w, k_w, v_w, Qall, Ktall, Vall);
    attn_c_k<<<2688 + 1280, 256, 0, stream>>>(Qall, Ktall, Vall, Oall);
    padU_c_k<<<(121248 + 255) / 256, 256, 0, stream>>>(Uall, Upall);
    projpos_c_k<<<1473, 256, 0, stream>>>(Oall, Uall, Upall, proj_w, pwb,
                                          bnp_g, bnp_b, Aall);

    ring_zero2_k<<<(2 * N_ * 404 * 192 + 255) / 256, 256, 0, stream>>>(Xb, Xb2);
    fold_c_k<<<(3840000 + 255) / 256, 256, 0, stream>>>(Aall, Xb);

    conv3x3_mfma_k<true, true><<<NB3_, 256, 0, stream>>>(
        Xb, w2b, bn2_g, bn2_b, x1, nullptr, Xb2);
    conv3x3_mfma_k<false, false><<<NB3_, 256, 0, stream>>>(
        Xb2, w3b, bn3_g, bn3_b, nullptr, (float*)d_out, nullptr);
}